// Round 15
// baseline (364.390 us; speedup 1.0000x reference)
//
#include <hip/hip_runtime.h>
#include <math.h>

#define NBS 1600      // B*S
#define LL 20
#define EE 300
#define NH 16
#define VD 16
#define HID 256
#define QD 200

typedef short bf16x8 __attribute__((ext_vector_type(8)));
typedef float f32x4 __attribute__((ext_vector_type(4)));

__device__ __forceinline__ short f2b(float f) {
    union { float f; unsigned u; } c; c.f = f;
    unsigned r = (c.u + 0x7FFFu + ((c.u >> 16) & 1u)) >> 16;  // RNE
    return (short)r;
}

__device__ __forceinline__ float b2f(short s) {
    union { unsigned u; float f; } c; c.u = ((unsigned)(unsigned short)s) << 16;
    return c.f;
}

__device__ __forceinline__ float ftanh(float a) {
    a = fminf(fmaxf(a, -15.f), 15.f);
    float t = __expf(2.f * a);
    return (t - 1.f) / (t + 1.f);
}

__device__ __forceinline__ void gload16(const short* g, short* l) {
    __builtin_amdgcn_global_load_lds(
        (const __attribute__((address_space(1))) unsigned int*)g,
        (__attribute__((address_space(3))) unsigned int*)l, 16, 0, 0);
}

// ===========================================================================
// Build kernels
// ===========================================================================

// news/emb -> Xb bf16 [32000][320]; col300 = 1.0 (bias channel), 301..319 = 0
__global__ void build_xb_lin(const int* __restrict__ news, const float* __restrict__ emb,
                             short* __restrict__ Xb) {
    int idx = blockIdx.x * 256 + threadIdx.x;
    if (idx >= 32000 * 80) return;
    int i = idx / 80, e4 = (idx % 80) * 4;
    short4 o;
    if (e4 < 300) {
        const float4 v = *reinterpret_cast<const float4*>(emb + (size_t)news[i] * EE + e4);
        o.x = f2b(v.x); o.y = f2b(v.y); o.z = f2b(v.z); o.w = f2b(v.w);
    } else if (e4 == 300) {
        o.x = (short)0x3F80; o.y = 0; o.z = 0; o.w = 0;
    } else {
        o.x = o.y = o.z = o.w = 0;
    }
    *reinterpret_cast<short4*>(Xb + (size_t)i * 320 + e4) = o;
}

// Wq [n][e][f] -> WqT bf16 [5120 rows = n*320+f][320 cols = e], col300 = qB
__global__ __launch_bounds__(1024) void build_wqt_lin(
    const float* __restrict__ qW, const float* __restrict__ qB, short* __restrict__ WqT)
{
    __shared__ float t[32][33];
    const int n = blockIdx.z;
    const int e0 = blockIdx.x * 32, f0 = blockIdx.y * 32;
    const int tx = threadIdx.x, ty = threadIdx.y;
    const int e = e0 + ty, f = f0 + tx;
    t[ty][tx] = (e < EE && f < EE) ? qW[((size_t)n * EE + e) * EE + f] : 0.f;
    __syncthreads();
    const int fo = f0 + ty, eo = e0 + tx;
    float val;
    if (fo >= EE)      val = 0.f;
    else if (eo < EE)  val = t[tx][ty];
    else if (eo == EE) val = qB[n * EE + fo];
    else               val = 0.f;
    WqT[((size_t)n * 320 + fo) * 320 + eo] = f2b(val);
}

// Wv [n][e][v] -> WvT bf16 [256][320], col300 = vB
__global__ void build_wvt(const float* __restrict__ vW, const float* __restrict__ vB,
                          short* __restrict__ WvT) {
    int idx = blockIdx.x * 256 + threadIdx.x;
    if (idx >= 256 * 320) return;
    int c = idx / 320, e = idx % 320;
    int n = c >> 4, vd = c & 15;
    float val = (e < EE) ? vW[((size_t)n * EE + e) * VD + vd]
                         : (e == EE ? vB[n * VD + vd] : 0.f);
    WvT[idx] = f2b(val);
}

// keyW [200][256] fp32 -> bf16 kwb2 [256][256] (rows >=200 zero)
__global__ void conv_kw(const float* __restrict__ keyW, short* __restrict__ kwb) {
    int idx = blockIdx.x * 256 + threadIdx.x;
    if (idx >= 256 * 256) return;
    int d = idx >> 8;
    kwb[idx] = (d < QD) ? f2b(keyW[idx]) : (short)0;
}

// xv = Xb * WvT^T : [32000][256] bf16.  128x128 tile, 4 waves.
__global__ __launch_bounds__(256) void gemm_xv(
    const short* __restrict__ Xb, const short* __restrict__ WvT, short* __restrict__ xv)
{
    const int nt0 = blockIdx.x * 128;
    const size_t mt0 = (size_t)blockIdx.y * 128;
    const int tid = threadIdx.x, wave = tid >> 6, lane = tid & 63;
    const int lr = lane & 15, lg = lane >> 4;
    const int wm = wave & 1, wn = wave >> 1;

    __shared__ short As[128][68];
    __shared__ short Bs[128][68];
    f32x4 acc[4][4] = {};

    for (int ks = 0; ks < 5; ++ks) {
        __syncthreads();
        for (int u = 0; u < 4; ++u) {
            int idx = u * 256 + tid;
            int rr = idx >> 3, c8 = idx & 7;
            *reinterpret_cast<bf16x8*>(&As[rr][c8 * 8]) =
                *reinterpret_cast<const bf16x8*>(Xb + (mt0 + rr) * 320 + ks * 64 + c8 * 8);
            *reinterpret_cast<bf16x8*>(&Bs[rr][c8 * 8]) =
                *reinterpret_cast<const bf16x8*>(WvT + (size_t)(nt0 + rr) * 320 + ks * 64 + c8 * 8);
        }
        __syncthreads();
        #pragma unroll
        for (int kk = 0; kk < 2; ++kk) {
            bf16x8 af[4], bfv[4];
            #pragma unroll
            for (int f = 0; f < 4; ++f)
                af[f] = *reinterpret_cast<const bf16x8*>(&As[wm * 64 + f * 16 + lr][kk * 32 + lg * 8]);
            #pragma unroll
            for (int f = 0; f < 4; ++f)
                bfv[f] = *reinterpret_cast<const bf16x8*>(&Bs[wn * 64 + f * 16 + lr][kk * 32 + lg * 8]);
            #pragma unroll
            for (int i = 0; i < 4; ++i)
                #pragma unroll
                for (int j = 0; j < 4; ++j)
                    acc[i][j] = __builtin_amdgcn_mfma_f32_16x16x32_bf16(af[i], bfv[j], acc[i][j], 0, 0, 0);
        }
    }
    #pragma unroll
    for (int i = 0; i < 4; ++i)
        #pragma unroll
        for (int j = 0; j < 4; ++j)
            #pragma unroll
            for (int r = 0; r < 4; ++r)
                xv[(mt0 + wm * 64 + i * 16 + lg * 4 + r) * 256 + nt0 + wn * 64 + j * 16 + lr]
                    = f2b(acc[i][j][r]);
}

// ---------------------------------------------------------------------------
// qsv v2: fused q-GEMM + scores + softmax + v.  One block per (4 bs, head).
// grid (400,16), 256 thr, 4 waves.  Same as r14 except atw now ALIASES each
// wave's own dead qs row-region (rows 20b.. are wave-private and dead after
// that wave's scores loop; softmax values held in registers first).  LDS
// drops 60.5 -> 51.8 KB => 3 blocks/CU (12 waves/CU for barrier-drain
// overlap, m114).
// ---------------------------------------------------------------------------
__global__ __launch_bounds__(256, 3) void qsv(
    const short* __restrict__ Xb,    // [32000][320]
    const short* __restrict__ WqT,   // [5120][320]
    const short* __restrict__ xv,    // [32000][256]
    float*       __restrict__ out1,  // [32000][256]
    short*       __restrict__ mhb)   // [32000][256] bf16
{
    const int g = blockIdx.x;        // 4-bs group
    const int n = blockIdx.y;        // head
    const int tid = threadIdx.x, wave = tid >> 6, lane = tid & 63;
    const int lr = lane & 15, lg = lane >> 4;
    const size_t row0 = (size_t)g * 80;

    // [0,12800): staging (A [80][32] @0, B [320][32] @2560)
    // [0,25920): qs [80][324] after GEMM (aliases staging)
    // atw[b] aliases qs rows 20b.. (wave-private, dead after own scores)
    __shared__ short lds[25920];

    // staging seg map: 1600 segs of 16B; thread handles s = k*256+tid
    const short* gp[7];
    int dsto[7];
    #pragma unroll
    for (int k = 0; k < 7; ++k) {
        const int s = k * 256 + tid;
        if (s < 320) {
            gp[k]   = Xb + (row0 + (s >> 2)) * 320 + (s & 3) * 8;
            dsto[k] = s * 8;
        } else if (s < 1600) {
            const int s2 = s - 320;
            gp[k]   = WqT + (size_t)(n * 320 + (s2 >> 2)) * 320 + (s2 & 3) * 8;
            dsto[k] = 2560 + s2 * 8;
        } else {
            gp[k] = Xb; dsto[k] = 0;   // unused (k==6, tid>=64)
        }
    }

    // prefetch xv B-frag for v-phase (wave = bs)
    const int b = wave;
    bf16x8 bv;
    #pragma unroll
    for (int j = 0; j < 8; ++j) {
        int m = lg * 8 + j; if (m > 19) m = 19;   // attn cols >=20 are zero
        bv[j] = xv[(row0 + b * 20 + m) * 256 + n * 16 + lr];
    }

    // ---- q-GEMM K-loop (m97 recipe) ----
    f32x4 acc[5][5] = {};
    for (int ks = 0; ks < 10; ++ks) {
        __syncthreads();                     // staging region free
        const int ko = ks * 32;
        #pragma unroll
        for (int k = 0; k < 6; ++k)
            gload16(gp[k] + ko, lds + dsto[k]);
        if (tid < 64)
            gload16(gp[6] + ko, lds + dsto[6]);
        __syncthreads();                     // glds drained
        bf16x8 af[5], bfr[5];
        #pragma unroll
        for (int i = 0; i < 5; ++i)
            af[i] = *reinterpret_cast<const bf16x8*>(lds + (i * 16 + lr) * 32 + lg * 8);
        #pragma unroll
        for (int j = 0; j < 5; ++j)
            bfr[j] = *reinterpret_cast<const bf16x8*>(lds + 2560 + (wave * 80 + j * 16 + lr) * 32 + lg * 8);
        #pragma unroll
        for (int i = 0; i < 5; ++i)
            #pragma unroll
            for (int j = 0; j < 5; ++j)
                acc[i][j] = __builtin_amdgcn_mfma_f32_16x16x32_bf16(af[i], bfr[j], acc[i][j], 0, 0, 0);
    }
    __syncthreads();   // staging reads done -> safe to overwrite with qs

    // ---- acc -> qs [80][324]; wave w owns cols [80w, 80w+80) ----
    #pragma unroll
    for (int i = 0; i < 5; ++i)
        #pragma unroll
        for (int j = 0; j < 5; ++j)
            #pragma unroll
            for (int r = 0; r < 4; ++r)
                lds[(i * 16 + lg * 4 + r) * 324 + wave * 80 + j * 16 + lr] = f2b(acc[i][j][r]);

    // ---- bulk-prefetch scores-phase X fragments (fly over the barrier) ----
    const int rA0 = b * 20 + lr;
    int rA1 = b * 20 + 16 + lr; if (rA1 > 79) rA1 = 79;
    bf16x8 xpre0[10], xpre1[10];
    #pragma unroll
    for (int ks = 0; ks < 10; ++ks) {
        xpre0[ks] = *reinterpret_cast<const bf16x8*>(Xb + (row0 + rA0) * 320 + ks * 32 + lg * 8);
        xpre1[ks] = *reinterpret_cast<const bf16x8*>(Xb + (row0 + rA1) * 320 + ks * 32 + lg * 8);
    }
    __syncthreads();   // qs complete

    // ---- scores + in-register softmax: wave = bs; results to registers ----
    float w0[2][4], w1[2][4];
    {
        f32x4 s[2][2] = {};
        #pragma unroll
        for (int ks = 0; ks < 10; ++ks) {
            const int kc = ks * 32 + lg * 8;
            bf16x8 a0 = *reinterpret_cast<const bf16x8*>(lds + rA0 * 324 + kc);
            bf16x8 a1 = *reinterpret_cast<const bf16x8*>(lds + rA1 * 324 + kc);
            s[0][0] = __builtin_amdgcn_mfma_f32_16x16x32_bf16(a0, xpre0[ks], s[0][0], 0, 0, 0);
            s[0][1] = __builtin_amdgcn_mfma_f32_16x16x32_bf16(a0, xpre1[ks], s[0][1], 0, 0, 0);
            s[1][0] = __builtin_amdgcn_mfma_f32_16x16x32_bf16(a1, xpre0[ks], s[1][0], 0, 0, 0);
            s[1][1] = __builtin_amdgcn_mfma_f32_16x16x32_bf16(a1, xpre1[ks], s[1][1], 0, 0, 0);
        }

        const float scl = 0.057735026918962584f;  // 1/sqrt(300)
        #pragma unroll
        for (int mts = 0; mts < 2; ++mts) {
            #pragma unroll
            for (int r = 0; r < 4; ++r) {
                float v0 = s[mts][0][r] * scl;
                float v1 = s[mts][1][r] * scl;
                float mx = (lr < 4) ? fmaxf(v0, v1) : v0;
                mx = fmaxf(mx, __shfl_xor(mx, 1));
                mx = fmaxf(mx, __shfl_xor(mx, 2));
                mx = fmaxf(mx, __shfl_xor(mx, 4));
                mx = fmaxf(mx, __shfl_xor(mx, 8));
                float e0 = __expf(v0 - mx);
                float e1 = (lr < 4) ? __expf(v1 - mx) : 0.f;
                float sm = e0 + e1;
                sm += __shfl_xor(sm, 1);
                sm += __shfl_xor(sm, 2);
                sm += __shfl_xor(sm, 4);
                sm += __shfl_xor(sm, 8);
                const float inv = 1.f / sm;
                w0[mts][r] = e0 * inv;
                w1[mts][r] = e1 * inv;
            }
        }
    }

    // ---- atw aliases own qs rows (dead now).  Zero, then write attn. ----
    short* atw = lds + b * 6480;   // 1088 shorts needed, 6480 available
    {
        int* az = reinterpret_cast<int*>(atw);
        #pragma unroll
        for (int i = 0; i < 9; ++i) {
            const int ix = lane + i * 64;
            if (ix < 544) az[ix] = 0;
        }
    }
    #pragma unroll
    for (int mts = 0; mts < 2; ++mts)
        #pragma unroll
        for (int r = 0; r < 4; ++r) {
            const int row = mts * 16 + lg * 4 + r;
            if (row < LL) {
                atw[row * 34 + lr]      = f2b(w0[mts][r]);
                atw[row * 34 + 16 + lr] = f2b(w1[mts][r]);   // lr>=4 writes 0
            }
        }
    // wave-private atw: ds-write -> ds-read ordering via lgkmcnt

    // ---- v = attn * xv ----
    bf16x8 va0 = *reinterpret_cast<const bf16x8*>(atw + lr * 34 + lg * 8);
    bf16x8 va1 = *reinterpret_cast<const bf16x8*>(atw + (16 + lr) * 34 + lg * 8);
    f32x4 z = {0.f, 0.f, 0.f, 0.f};
    f32x4 v0 = __builtin_amdgcn_mfma_f32_16x16x32_bf16(va0, bv, z, 0, 0, 0);
    f32x4 v1 = __builtin_amdgcn_mfma_f32_16x16x32_bf16(va1, bv, z, 0, 0, 0);
    #pragma unroll
    for (int r = 0; r < 4; ++r) {
        const int rowl = lg * 4 + r;
        const size_t o0 = (row0 + b * 20 + rowl) * 256 + n * 16 + lr;
        out1[o0] = v0[r];
        mhb[o0] = f2b(v0[r]);
        const int rowl1 = 16 + lg * 4 + r;
        if (rowl1 < LL) {
            const size_t o1 = (row0 + b * 20 + rowl1) * 256 + n * 16 + lr;
            out1[o1] = v1[r];
            mhb[o1] = f2b(v1[r]);
        }
    }
}

// ---------------------------------------------------------------------------
// gemm_ak: ak[32000][256] = mhb * kwb2^T.  m97 structure, K=256.
// ---------------------------------------------------------------------------
__global__ __launch_bounds__(256, 4) void gemm_ak(
    const short* __restrict__ mhb,   // [32000][256]
    const short* __restrict__ kwb,   // [256][256]
    short*       __restrict__ ak)    // [32000][256]
{
    const int nt0 = blockIdx.x * 128;
    const int mt0 = blockIdx.y * 128;
    const int tid = threadIdx.x, wave = tid >> 6, lane = tid & 63;
    const int lr = lane & 15, lg = lane >> 4;
    const int wm = wave & 1, wn = wave >> 1;

    __shared__ short sAB[8192];

    const int rA = tid >> 2, c = tid & 3;
    const short* aS0 = mhb + (size_t)(mt0 + rA) * 256 + c * 8;
    const short* aS1 = aS0 + (size_t)64 * 256;
    const short* bS0 = kwb + (size_t)(nt0 + rA) * 256 + c * 8;
    const short* bS1 = bS0 + (size_t)64 * 256;
    short* d0 = sAB + tid * 8;
    short* d1 = sAB + (tid + 256) * 8;
    short* d2 = sAB + (tid + 512) * 8;
    short* d3 = sAB + (tid + 768) * 8;

    f32x4 acc[4][4] = {};
    for (int ks = 0; ks < 8; ++ks) {
        __syncthreads();
        const int ko = ks * 32;
        gload16(aS0 + ko, d0);
        gload16(aS1 + ko, d1);
        gload16(bS0 + ko, d2);
        gload16(bS1 + ko, d3);
        __syncthreads();
        bf16x8 af[4], bfr[4];
        #pragma unroll
        for (int i = 0; i < 4; ++i)
            af[i] = *reinterpret_cast<const bf16x8*>(sAB + (wm * 64 + i * 16 + lr) * 32 + lg * 8);
        #pragma unroll
        for (int j = 0; j < 4; ++j)
            bfr[j] = *reinterpret_cast<const bf16x8*>(sAB + 4096 + (wn * 64 + j * 16 + lr) * 32 + lg * 8);
        #pragma unroll
        for (int i = 0; i < 4; ++i)
            #pragma unroll
            for (int j = 0; j < 4; ++j)
                acc[i][j] = __builtin_amdgcn_mfma_f32_16x16x32_bf16(af[i], bfr[j], acc[i][j], 0, 0, 0);
    }

    #pragma unroll
    for (int i = 0; i < 4; ++i)
        #pragma unroll
        for (int j = 0; j < 4; ++j)
            #pragma unroll
            for (int r = 0; r < 4; ++r)
                ak[(size_t)(mt0 + wm * 64 + i * 16 + lg * 4 + r) * 256
                   + nt0 + wn * 64 + j * 16 + lr] = f2b(acc[i][j][r]);
}

// ---------------------------------------------------------------------------
// pool_light: per bs — tanh/dot reduce, softmax, weighted sum.
// ---------------------------------------------------------------------------
__global__ __launch_bounds__(256) void pool_light(
    const short* __restrict__ ak,     // [32000][256] bf16
    const float* __restrict__ out1,   // mh fp32
    const float* __restrict__ keyB,   // [200]
    const float* __restrict__ query,  // [200]
    float*       __restrict__ out2)   // [NBS][256]
{
    const int bs = blockIdx.x;
    const int tid = threadIdx.x, wave = tid >> 6, lane = tid & 63;

    __shared__ float s2[LL];

    #pragma unroll
    for (int li = 0; li < 5; ++li) {
        const int l = wave * 5 + li;
        const short* ar = ak + ((size_t)bs * 20 + l) * 256;
        float acc = 0.f;
        #pragma unroll
        for (int it = 0; it < 4; ++it) {
            const int d = lane + it * 64;
            if (d < QD) {
                const float t = ftanh(b2f(ar[d]) + keyB[d]);
                acc = fmaf(query[d], t, acc);
            }
        }
        acc += __shfl_xor(acc, 32);
        acc += __shfl_xor(acc, 16);
        acc += __shfl_xor(acc, 8);
        acc += __shfl_xor(acc, 4);
        acc += __shfl_xor(acc, 2);
        acc += __shfl_xor(acc, 1);
        if (lane == 0) s2[l] = acc * 0.07071067811865475f;  // 1/sqrt(200)
    }
    __syncthreads();

    if (tid == 0) {
        float mx = -1e30f;
        #pragma unroll
        for (int l = 0; l < LL; ++l) mx = fmaxf(mx, s2[l]);
        float e[LL], sum = 0.f;
        #pragma unroll
        for (int l = 0; l < LL; ++l) { e[l] = __expf(s2[l] - mx); sum += e[l]; }
        const float inv = 1.f / sum;
        #pragma unroll
        for (int l = 0; l < LL; ++l) s2[l] = e[l] * inv;
    }
    __syncthreads();

    float o = 0.f;
    #pragma unroll
    for (int l = 0; l < LL; ++l)
        o = fmaf(s2[l], out1[((size_t)bs * 20 + l) * 256 + tid], o);
    out2[(size_t)bs * 256 + tid] = o;
}

// ===========================================================================
// FALLBACK (round-3, ~3.4 MB ws)
// ===========================================================================

#define XP 330
#define TP 42
#define AP 34

__global__ __launch_bounds__(1024) void transpose_qw(
    const float* __restrict__ qW, short* __restrict__ wqt)
{
    __shared__ float t[32][33];
    const int n = blockIdx.z;
    const int e0 = blockIdx.x * 32, f0 = blockIdx.y * 32;
    const int tx = threadIdx.x, ty = threadIdx.y;
    const int e = e0 + ty, f = f0 + tx;
    t[ty][tx] = (e < EE && f < EE) ? qW[(size_t)n * EE * EE + e * EE + f] : 0.f;
    __syncthreads();
    const int fo = f0 + ty, eo = e0 + tx;
    if (fo < 304)
        wqt[(size_t)n * 304 * 320 + fo * 320 + eo] = f2b(t[tx][ty]);
}

__global__ void conv_vw(const float* __restrict__ vW, short* __restrict__ wvt) {
    int idx = blockIdx.x * 256 + threadIdx.x;
    if (idx >= NH * VD * 320) return;
    int e = idx % 320;
    int v = (idx / 320) % VD;
    int n = idx / (320 * VD);
    wvt[idx] = (e < EE) ? f2b(vW[(size_t)n * EE * VD + e * VD + v]) : (short)0;
}

__global__ __launch_bounds__(512) void nrms_attn_mfma(
    const int*   __restrict__ news,
    const float* __restrict__ emb,
    const short* __restrict__ wqt,
    const float* __restrict__ qB,
    const short* __restrict__ wvt,
    const float* __restrict__ vB,
    float*       __restrict__ out1)
{
    const int bs   = blockIdx.x;
    const int tid  = threadIdx.x;
    const int wave = tid >> 6;
    const int lane = tid & 63;
    const int lr   = lane & 15;
    const int lg   = lane >> 4;

    __shared__ short xs[32][XP];
    __shared__ short xT[320][TP];
    __shared__ short qs[32][XP];
    __shared__ float sc[32][33];
    __shared__ short at[32][AP];

    {
        int* z = (int*)&xs[0][0];
        for (int i = tid; i < 32 * XP / 2; i += 512) z[i] = 0;
        z = (int*)&qs[0][0];
        for (int i = tid; i < 32 * XP / 2; i += 512) z[i] = 0;
        z = (int*)&xT[0][0];
        for (int i = tid; i < 320 * TP / 2; i += 512) z[i] = 0;
    }
    __syncthreads();

    for (int idx = tid; idx < LL * 75; idx += 512) {
        const int l = idx / 75, e4 = (idx % 75) * 4;
        const int row = news[bs * LL + l];
        const float4 v = *reinterpret_cast<const float4*>(emb + (size_t)row * EE + e4);
        const short b0 = f2b(v.x), b1 = f2b(v.y), b2 = f2b(v.z), b3 = f2b(v.w);
        xs[l][e4] = b0; xs[l][e4 + 1] = b1; xs[l][e4 + 2] = b2; xs[l][e4 + 3] = b3;
        xT[e4][l] = b0; xT[e4 + 1][l] = b1; xT[e4 + 2][l] = b2; xT[e4 + 3][l] = b3;
    }
    __syncthreads();

    for (int n = 0; n < NH; ++n) {
        const short* wq = wqt + (size_t)n * 304 * 320;

        for (int p = wave; p < 19; p += 8) {
            f32x4 acc0 = {0.f, 0.f, 0.f, 0.f};
            f32x4 acc1 = {0.f, 0.f, 0.f, 0.f};
            const short* a0p = &xs[lr][lg * 8];
            const short* a1p = &xs[16 + lr][lg * 8];
            const short* bp  = wq + (p * 16 + lr) * 320 + lg * 8;
            #pragma unroll
            for (int k = 0; k < 10; ++k) {
                bf16x8 b  = *reinterpret_cast<const bf16x8*>(bp + k * 32);
                bf16x8 a0 = *reinterpret_cast<const bf16x8*>(a0p + k * 32);
                bf16x8 a1 = *reinterpret_cast<const bf16x8*>(a1p + k * 32);
                acc0 = __builtin_amdgcn_mfma_f32_16x16x32_bf16(a0, b, acc0, 0, 0, 0);
                acc1 = __builtin_amdgcn_mfma_f32_16x16x32_bf16(a1, b, acc1, 0, 0, 0);
            }
            const int col = p * 16 + lr;
            const float bias = (col < EE) ? qB[n * EE + col] : 0.f;
            #pragma unroll
            for (int r = 0; r < 4; ++r) {
                qs[lg * 4 + r][col]      = f2b(acc0[r] + bias);
                qs[16 + lg * 4 + r][col] = f2b(acc1[r] + bias);
            }
        }
        __syncthreads();

        if (wave < 4) {
            const int mt = wave & 1, nt = wave >> 1;
            f32x4 acc = {0.f, 0.f, 0.f, 0.f};
            const short* ap = &qs[mt * 16 + lr][lg * 8];
            const short* bp = &xs[nt * 16 + lr][lg * 8];
            #pragma unroll
            for (int k = 0; k < 10; ++k) {
                bf16x8 a = *reinterpret_cast<const bf16x8*>(ap + k * 32);
                bf16x8 b = *reinterpret_cast<const bf16x8*>(bp + k * 32);
                acc = __builtin_amdgcn_mfma_f32_16x16x32_bf16(a, b, acc, 0, 0, 0);
            }
            #pragma unroll
            for (int r = 0; r < 4; ++r)
                sc[mt * 16 + lg * 4 + r][nt * 16 + lr] = acc[r] * 0.057735026918962584f;
        }
        __syncthreads();

        if (tid < LL) {
            float mx = -1e30f;
            #pragma unroll
            for (int m = 0; m < LL; ++m) mx = fmaxf(mx, sc[tid][m]);
            float ev[LL], sum = 0.f;
            #pragma unroll
            for (int m = 0; m < LL; ++m) { ev[m] = __expf(sc[tid][m] - mx); sum += ev[m]; }
            const float inv = 1.f / sum;
            #pragma unroll
            for (int m = 0; m < LL; ++m) at[tid][m] = f2b(ev[m] * inv);
            #pragma unroll
            for (int m = LL; m < 32; ++m) at[tid][m] = 0;
        } else if (tid < 32) {
            int* zr = (int*)&at[tid][0];
            #pragma unroll
            for (int m = 0; m < 16; ++m) zr[m] = 0;
        }
        __syncthreads();

        for (int p = wave; p < 19; p += 8) {
            bf16x8 b  = *reinterpret_cast<const bf16x8*>(&xT[p * 16 + lr][lg * 8]);
            bf16x8 a0 = *reinterpret_cast<const bf16x8*>(&at[lr][lg * 8]);
            bf16x8 a1 = *reinterpret_cast<const bf16x8*>(&at[16 + lr][lg * 8]);
            f32x4 z = {0.f, 0.f, 0.f, 0.f};
            f32x4 c0 = __builtin_amdgcn_mfma_f32_16x16x32_bf16(a0, b, z, 0, 0, 0);
            f32x4 c1 = __builtin_amdgcn_mfma_f32_16x16x32_bf16(a1, b, z, 0, 0, 0);
            const int col = p * 16 + lr;
            #pragma unroll
            for (int r = 0; r < 4; ++r) {
                qs[lg * 4 + r][col]      = f2b(c0[r]);
                qs[16 + lg * 4 + r][col] = f2b(c1[r]);
            }
        }
        __syncthreads();

        if (wave < 2) {
            const int mt = wave;
            f32x4 acc = {0.f, 0.f, 0.f, 0.f};
            const short* ap = &qs[mt * 16 + lr][lg * 8];
            const short* bp = wvt + (size_t)n * VD * 320 + lr * 320 + lg * 8;
            #pragma unroll
            for (int k = 0; k < 10; ++k) {
                bf16x8 a = *reinterpret_cast<const bf16x8*>(ap + k * 32);
                bf16x8 b = *reinterpret_cast<const bf16x8*>(bp + k * 32);
                acc = __builtin_amdgcn_mfma_f32_16x16x32_bf16(a, b, acc, 0, 0, 0);
            }
            #pragma unroll
            for (int r = 0; r < 4; ++r) {
                const int row = mt * 16 + lg * 4 + r;
                if (row < LL)
                    out1[((size_t)bs * LL + row) * HID + n * VD + lr] = acc[r] + vB[n * VD + lr];
            }
        }
        __syncthreads();
    }
}

__global__ __launch_bounds__(256) void nrms_pool_mfma(
    const float* __restrict__ out1,
    const short* __restrict__ kwb,    // [256][256] bf16 (rows >=200 zero)
    const float* __restrict__ keyB,
    const float* __restrict__ query,
    float*       __restrict__ out2)
{
    const int bs   = blockIdx.x;
    const int tid  = threadIdx.x;
    const int wave = tid >> 6;
    const int lane = tid & 63;
    const int lr   = lane & 15;
    const int lg   = lane >> 4;

    __shared__ float mh[LL][257];
    __shared__ short mhbl[32][264];
    __shared__ float s2p[32];

    for (int i = tid; i < 12 * 128; i += 256) {
        const int r = 20 + i / 128, c = (i % 128) * 2;
        *reinterpret_cast<int*>(&mhbl[r][c]) = 0;
    }
    if (tid < 32) s2p[tid] = 0.f;

    for (int idx = tid; idx < LL * 64; idx += 256) {
        const int l = idx >> 6, h4 = (idx & 63) * 4;
        const float4 v = *reinterpret_cast<const float4*>(out1 + ((size_t)bs * LL + l) * HID + h4);
        mh[l][h4] = v.x; mh[l][h4 + 1] = v.y; mh[l][h4 + 2] = v.z; mh[l][h4 + 3] = v.w;
        mhbl[l][h4] = f2b(v.x); mhbl[l][h4 + 1] = f2b(v.y);
        mhbl[l][h4 + 2] = f2b(v.z); mhbl[l][h4 + 3] = f2b(v.w);
    }
    __syncthreads();

    for (int t = wave; t < 26; t += 4) {
        const int mt = t & 1, nt = t >> 1;
        f32x4 acc = {0.f, 0.f, 0.f, 0.f};
        const short* ap = &mhbl[mt * 16 + lr][lg * 8];
        const short* bp = kwb + (nt * 16 + lr) * 256 + lg * 8;
        #pragma unroll
        for (int k = 0; k < 8; ++k) {
            bf16x8 a = *reinterpret_cast<const bf16x8*>(ap + k * 32);
            bf16x8 b = *reinterpret_cast<const bf16x8*>(bp + k * 32);
            acc = __builtin_amdgcn_mfma_f32_16x16x32_bf16(a, b, acc, 0, 0, 0);
        }
        const int d = nt * 16 + lr;
        const float qd = (d < QD) ? query[d] : 0.f;
        const float kb = (d < QD) ? keyB[d] : 0.f;
        float vals[4];
        #pragma unroll
        for (int r = 0; r < 4; ++r) vals[r] = qd * ftanh(acc[r] + kb);
        #pragma unroll
        for (int off = 1; off < 16; off <<= 1) {
            #pragma unroll
            for (int r = 0; r < 4; ++r) vals[r] += __shfl_xor(vals[r], off);
        }
        if (lr == 0) {
            #pragma unroll
            for (int r = 0; r < 4; ++r)
                atomicAdd(&s2p[mt * 16 + lg * 4 + r], vals[r]);
        }
    }
    __syncthreads();

    if (tid == 0) {
        float mx = -1e30f;
        #pragma unroll
        for (int l = 0; l < LL; ++l) mx = fmaxf(mx, s2p[l] * 0.07071067811865475f);
        float sum = 0.f;
        float e[LL];
        #pragma unroll
        for (int l = 0; l < LL; ++l) { e[l] = __expf(s2p[l] * 0.07071067811865475f - mx); sum += e[l]; }
        const float inv = 1.f / sum;
        #pragma unroll
        for (int l = 0; l < LL; ++l) s2p[l] = e[l] * inv;
    }
    __syncthreads();

    {
        const int h = tid;
        float acc = 0.f;
        #pragma unroll
        for (int l = 0; l < LL; ++l) acc = fmaf(s2p[l], mh[l][h], acc);
        out2[(size_t)bs * HID + h] = acc;
    }
}

// ===========================================================================

extern "C" void kernel_launch(void* const* d_in, const int* in_sizes, int n_in,
                              void* d_out, int out_size, void* d_ws, size_t ws_size,
                              hipStream_t stream) {
    const int*   news  = (const int*)d_in[0];
    const float* emb   = (const float*)d_in[1];
    const float* qW    = (const float*)d_in[2];
    const float* qB    = (const float*)d_in[3];
    const float* vW    = (const float*)d_in[4];
    const float* vB    = (const float*)d_in[5];
    const float* keyW  = (const float*)d_in[6];
    const float* keyB  = (const float*)d_in[7];
    const float* query = (const float*)d_in[8];

    float* out1 = (float*)d_out;            // news_embedding: 8192000 floats
    float* out2 = out1 + 8192000;           // news_repr: 409600 floats

    // base (shorts): Xb 10.24M, WqT 1.6384M, WvT 81920, xv 8.192M,
    //                kwb2 65536, mhb 8.192M, ak 8.192M  = 36,601,856 (73.2 MB)
    const size_t BASE_SH = 10240000ull + 1638400 + 81920 + 8192000
                         + 65536 + 8192000 + 8192000;
    const size_t BASE_B  = BASE_SH * 2;

    if (ws_size >= BASE_B) {
        short* Xb   = (short*)d_ws;
        short* WqT  = Xb + 10240000;
        short* WvT  = WqT + 1638400;
        short* xv   = WvT + 81920;
        short* kwb2 = xv + 8192000;
        short* mhb  = kwb2 + 65536;
        short* ak   = mhb + 8192000;

        hipLaunchKernelGGL(build_xb_lin, dim3(10000), dim3(256), 0, stream, news, emb, Xb);
        hipLaunchKernelGGL(build_wqt_lin, dim3(10, 10, 16), dim3(32, 32), 0, stream, qW, qB, WqT);
        hipLaunchKernelGGL(build_wvt, dim3(320), dim3(256), 0, stream, vW, vB, WvT);
        hipLaunchKernelGGL(conv_kw, dim3(256), dim3(256), 0, stream, keyW, kwb2);
        hipLaunchKernelGGL(gemm_xv, dim3(2, 250), dim3(256), 0, stream, Xb, WvT, xv);
        hipLaunchKernelGGL(qsv, dim3(400, 16), dim3(256), 0, stream,
                           Xb, WqT, xv, out1, mhb);
        hipLaunchKernelGGL(gemm_ak, dim3(2, 250), dim3(256), 0, stream, mhb, kwb2, ak);
        hipLaunchKernelGGL(pool_light, dim3(NBS), dim3(256), 0, stream,
                           ak, out1, keyB, query, out2);
    } else {
        short* wqt  = (short*)d_ws;
        short* wvt  = wqt + (size_t)NH * 304 * 320;
        short* kwb2 = wvt + (size_t)NH * VD * 320;

        hipLaunchKernelGGL(transpose_qw, dim3(10, 10, 16), dim3(32, 32), 0, stream, qW, wqt);
        hipLaunchKernelGGL(conv_vw, dim3(320), dim3(256), 0, stream, vW, wvt);
        hipLaunchKernelGGL(conv_kw, dim3(256), dim3(256), 0, stream, keyW, kwb2);
        hipLaunchKernelGGL(nrms_attn_mfma, dim3(NBS), dim3(512), 0, stream,
                           news, emb, wqt, qB, wvt, vB, out1);
        hipLaunchKernelGGL(nrms_pool_mfma, dim3(NBS), dim3(256), 0, stream,
                           out1, kwb2, keyB, query, out2);
    }
}

// Round 16
// 272.996 us; speedup vs baseline: 1.3348x; 1.3348x over previous
//
#include <hip/hip_runtime.h>
#include <math.h>

#define NBS 1600      // B*S
#define LL 20
#define EE 300
#define NH 16
#define VD 16
#define HID 256
#define QD 200

typedef short bf16x8 __attribute__((ext_vector_type(8)));
typedef float f32x4 __attribute__((ext_vector_type(4)));

__device__ __forceinline__ short f2b(float f) {
    union { float f; unsigned u; } c; c.f = f;
    unsigned r = (c.u + 0x7FFFu + ((c.u >> 16) & 1u)) >> 16;  // RNE
    return (short)r;
}

__device__ __forceinline__ float b2f(short s) {
    union { unsigned u; float f; } c; c.u = ((unsigned)(unsigned short)s) << 16;
    return c.f;
}

__device__ __forceinline__ float ftanh(float a) {
    a = fminf(fmaxf(a, -15.f), 15.f);
    float t = __expf(2.f * a);
    return (t - 1.f) / (t + 1.f);
}

__device__ __forceinline__ void gload16(const short* g, short* l) {
    __builtin_amdgcn_global_load_lds(
        (const __attribute__((address_space(1))) unsigned int*)g,
        (__attribute__((address_space(3))) unsigned int*)l, 16, 0, 0);
}

// ===========================================================================
// Build kernels
// ===========================================================================

// news/emb -> Xb bf16 [32000][320]; col300 = 1.0 (bias channel), 301..319 = 0
__global__ void build_xb_lin(const int* __restrict__ news, const float* __restrict__ emb,
                             short* __restrict__ Xb) {
    int idx = blockIdx.x * 256 + threadIdx.x;
    if (idx >= 32000 * 80) return;
    int i = idx / 80, e4 = (idx % 80) * 4;
    short4 o;
    if (e4 < 300) {
        const float4 v = *reinterpret_cast<const float4*>(emb + (size_t)news[i] * EE + e4);
        o.x = f2b(v.x); o.y = f2b(v.y); o.z = f2b(v.z); o.w = f2b(v.w);
    } else if (e4 == 300) {
        o.x = (short)0x3F80; o.y = 0; o.z = 0; o.w = 0;
    } else {
        o.x = o.y = o.z = o.w = 0;
    }
    *reinterpret_cast<short4*>(Xb + (size_t)i * 320 + e4) = o;
}

// Wq [n][e][f] -> WqT bf16 [5120 rows = n*320+f][320 cols = e], col300 = qB
__global__ __launch_bounds__(1024) void build_wqt_lin(
    const float* __restrict__ qW, const float* __restrict__ qB, short* __restrict__ WqT)
{
    __shared__ float t[32][33];
    const int n = blockIdx.z;
    const int e0 = blockIdx.x * 32, f0 = blockIdx.y * 32;
    const int tx = threadIdx.x, ty = threadIdx.y;
    const int e = e0 + ty, f = f0 + tx;
    t[ty][tx] = (e < EE && f < EE) ? qW[((size_t)n * EE + e) * EE + f] : 0.f;
    __syncthreads();
    const int fo = f0 + ty, eo = e0 + tx;
    float val;
    if (fo >= EE)      val = 0.f;
    else if (eo < EE)  val = t[tx][ty];
    else if (eo == EE) val = qB[n * EE + fo];
    else               val = 0.f;
    WqT[((size_t)n * 320 + fo) * 320 + eo] = f2b(val);
}

// Wv [n][e][v] -> WvT bf16 [256][320], col300 = vB
__global__ void build_wvt(const float* __restrict__ vW, const float* __restrict__ vB,
                          short* __restrict__ WvT) {
    int idx = blockIdx.x * 256 + threadIdx.x;
    if (idx >= 256 * 320) return;
    int c = idx / 320, e = idx % 320;
    int n = c >> 4, vd = c & 15;
    float val = (e < EE) ? vW[((size_t)n * EE + e) * VD + vd]
                         : (e == EE ? vB[n * VD + vd] : 0.f);
    WvT[idx] = f2b(val);
}

// keyW [200][256] fp32 -> bf16 kwb2 [256][256] (rows >=200 zero)
__global__ void conv_kw(const float* __restrict__ keyW, short* __restrict__ kwb) {
    int idx = blockIdx.x * 256 + threadIdx.x;
    if (idx >= 256 * 256) return;
    int d = idx >> 8;
    kwb[idx] = (d < QD) ? f2b(keyW[idx]) : (short)0;
}

// xv = Xb * WvT^T : [32000][256] bf16.  128x128 tile, 4 waves.
__global__ __launch_bounds__(256) void gemm_xv(
    const short* __restrict__ Xb, const short* __restrict__ WvT, short* __restrict__ xv)
{
    const int nt0 = blockIdx.x * 128;
    const size_t mt0 = (size_t)blockIdx.y * 128;
    const int tid = threadIdx.x, wave = tid >> 6, lane = tid & 63;
    const int lr = lane & 15, lg = lane >> 4;
    const int wm = wave & 1, wn = wave >> 1;

    __shared__ short As[128][68];
    __shared__ short Bs[128][68];
    f32x4 acc[4][4] = {};

    for (int ks = 0; ks < 5; ++ks) {
        __syncthreads();
        for (int u = 0; u < 4; ++u) {
            int idx = u * 256 + tid;
            int rr = idx >> 3, c8 = idx & 7;
            *reinterpret_cast<bf16x8*>(&As[rr][c8 * 8]) =
                *reinterpret_cast<const bf16x8*>(Xb + (mt0 + rr) * 320 + ks * 64 + c8 * 8);
            *reinterpret_cast<bf16x8*>(&Bs[rr][c8 * 8]) =
                *reinterpret_cast<const bf16x8*>(WvT + (size_t)(nt0 + rr) * 320 + ks * 64 + c8 * 8);
        }
        __syncthreads();
        #pragma unroll
        for (int kk = 0; kk < 2; ++kk) {
            bf16x8 af[4], bfv[4];
            #pragma unroll
            for (int f = 0; f < 4; ++f)
                af[f] = *reinterpret_cast<const bf16x8*>(&As[wm * 64 + f * 16 + lr][kk * 32 + lg * 8]);
            #pragma unroll
            for (int f = 0; f < 4; ++f)
                bfv[f] = *reinterpret_cast<const bf16x8*>(&Bs[wn * 64 + f * 16 + lr][kk * 32 + lg * 8]);
            #pragma unroll
            for (int i = 0; i < 4; ++i)
                #pragma unroll
                for (int j = 0; j < 4; ++j)
                    acc[i][j] = __builtin_amdgcn_mfma_f32_16x16x32_bf16(af[i], bfv[j], acc[i][j], 0, 0, 0);
        }
    }
    #pragma unroll
    for (int i = 0; i < 4; ++i)
        #pragma unroll
        for (int j = 0; j < 4; ++j)
            #pragma unroll
            for (int r = 0; r < 4; ++r)
                xv[(mt0 + wm * 64 + i * 16 + lg * 4 + r) * 256 + nt0 + wn * 64 + j * 16 + lr]
                    = f2b(acc[i][j][r]);
}

// ---------------------------------------------------------------------------
// qsv v3: fused q-GEMM + scores + softmax + v.  One block per (4 bs, head).
// grid (400,16), 256 thr, 4 waves.  LDS 51.8 KB (atw aliases each wave's own
// dead qs rows) => 3 blocks/CU by LDS.  launch_bounds(256,2): full register
// budget (no scratch spill; r15's (256,3) cap spilled 630 MB to scratch) —
// occupancy is set by LDS (3 blocks) since ~108 VGPR allows 16 waves/CU.
// ---------------------------------------------------------------------------
__global__ __launch_bounds__(256, 2) void qsv(
    const short* __restrict__ Xb,    // [32000][320]
    const short* __restrict__ WqT,   // [5120][320]
    const short* __restrict__ xv,    // [32000][256]
    float*       __restrict__ out1,  // [32000][256]
    short*       __restrict__ mhb)   // [32000][256] bf16
{
    const int g = blockIdx.x;        // 4-bs group
    const int n = blockIdx.y;        // head
    const int tid = threadIdx.x, wave = tid >> 6, lane = tid & 63;
    const int lr = lane & 15, lg = lane >> 4;
    const size_t row0 = (size_t)g * 80;

    // [0,12800): staging (A [80][32] @0, B [320][32] @2560)
    // [0,25920): qs [80][324] after GEMM (aliases staging)
    // atw[b] aliases qs rows 20b.. (wave-private, dead after own scores)
    __shared__ short lds[25920];

    // staging seg map: 1600 segs of 16B; thread handles s = k*256+tid
    const short* gp[7];
    int dsto[7];
    #pragma unroll
    for (int k = 0; k < 7; ++k) {
        const int s = k * 256 + tid;
        if (s < 320) {
            gp[k]   = Xb + (row0 + (s >> 2)) * 320 + (s & 3) * 8;
            dsto[k] = s * 8;
        } else if (s < 1600) {
            const int s2 = s - 320;
            gp[k]   = WqT + (size_t)(n * 320 + (s2 >> 2)) * 320 + (s2 & 3) * 8;
            dsto[k] = 2560 + s2 * 8;
        } else {
            gp[k] = Xb; dsto[k] = 0;   // unused (k==6, tid>=64)
        }
    }

    // prefetch xv B-frag for v-phase (wave = bs)
    const int b = wave;
    bf16x8 bv;
    #pragma unroll
    for (int j = 0; j < 8; ++j) {
        int m = lg * 8 + j; if (m > 19) m = 19;   // attn cols >=20 are zero
        bv[j] = xv[(row0 + b * 20 + m) * 256 + n * 16 + lr];
    }

    // ---- q-GEMM K-loop (m97 recipe) ----
    f32x4 acc[5][5] = {};
    for (int ks = 0; ks < 10; ++ks) {
        __syncthreads();                     // staging region free
        const int ko = ks * 32;
        #pragma unroll
        for (int k = 0; k < 6; ++k)
            gload16(gp[k] + ko, lds + dsto[k]);
        if (tid < 64)
            gload16(gp[6] + ko, lds + dsto[6]);
        __syncthreads();                     // glds drained
        bf16x8 af[5], bfr[5];
        #pragma unroll
        for (int i = 0; i < 5; ++i)
            af[i] = *reinterpret_cast<const bf16x8*>(lds + (i * 16 + lr) * 32 + lg * 8);
        #pragma unroll
        for (int j = 0; j < 5; ++j)
            bfr[j] = *reinterpret_cast<const bf16x8*>(lds + 2560 + (wave * 80 + j * 16 + lr) * 32 + lg * 8);
        #pragma unroll
        for (int i = 0; i < 5; ++i)
            #pragma unroll
            for (int j = 0; j < 5; ++j)
                acc[i][j] = __builtin_amdgcn_mfma_f32_16x16x32_bf16(af[i], bfr[j], acc[i][j], 0, 0, 0);
    }
    __syncthreads();   // staging reads done -> safe to overwrite with qs

    // ---- acc -> qs [80][324]; wave w owns cols [80w, 80w+80) ----
    #pragma unroll
    for (int i = 0; i < 5; ++i)
        #pragma unroll
        for (int j = 0; j < 5; ++j)
            #pragma unroll
            for (int r = 0; r < 4; ++r)
                lds[(i * 16 + lg * 4 + r) * 324 + wave * 80 + j * 16 + lr] = f2b(acc[i][j][r]);

    // ---- bulk-prefetch scores-phase X fragments (fly over the barrier) ----
    const int rA0 = b * 20 + lr;
    int rA1 = b * 20 + 16 + lr; if (rA1 > 79) rA1 = 79;
    bf16x8 xpre0[10], xpre1[10];
    #pragma unroll
    for (int ks = 0; ks < 10; ++ks) {
        xpre0[ks] = *reinterpret_cast<const bf16x8*>(Xb + (row0 + rA0) * 320 + ks * 32 + lg * 8);
        xpre1[ks] = *reinterpret_cast<const bf16x8*>(Xb + (row0 + rA1) * 320 + ks * 32 + lg * 8);
    }
    __syncthreads();   // qs complete

    // ---- scores + in-register softmax: wave = bs; results to registers ----
    float w0[2][4], w1[2][4];
    {
        f32x4 s[2][2] = {};
        #pragma unroll
        for (int ks = 0; ks < 10; ++ks) {
            const int kc = ks * 32 + lg * 8;
            bf16x8 a0 = *reinterpret_cast<const bf16x8*>(lds + rA0 * 324 + kc);
            bf16x8 a1 = *reinterpret_cast<const bf16x8*>(lds + rA1 * 324 + kc);
            s[0][0] = __builtin_amdgcn_mfma_f32_16x16x32_bf16(a0, xpre0[ks], s[0][0], 0, 0, 0);
            s[0][1] = __builtin_amdgcn_mfma_f32_16x16x32_bf16(a0, xpre1[ks], s[0][1], 0, 0, 0);
            s[1][0] = __builtin_amdgcn_mfma_f32_16x16x32_bf16(a1, xpre0[ks], s[1][0], 0, 0, 0);
            s[1][1] = __builtin_amdgcn_mfma_f32_16x16x32_bf16(a1, xpre1[ks], s[1][1], 0, 0, 0);
        }

        const float scl = 0.057735026918962584f;  // 1/sqrt(300)
        #pragma unroll
        for (int mts = 0; mts < 2; ++mts) {
            #pragma unroll
            for (int r = 0; r < 4; ++r) {
                float v0 = s[mts][0][r] * scl;
                float v1 = s[mts][1][r] * scl;
                float mx = (lr < 4) ? fmaxf(v0, v1) : v0;
                mx = fmaxf(mx, __shfl_xor(mx, 1));
                mx = fmaxf(mx, __shfl_xor(mx, 2));
                mx = fmaxf(mx, __shfl_xor(mx, 4));
                mx = fmaxf(mx, __shfl_xor(mx, 8));
                float e0 = __expf(v0 - mx);
                float e1 = (lr < 4) ? __expf(v1 - mx) : 0.f;
                float sm = e0 + e1;
                sm += __shfl_xor(sm, 1);
                sm += __shfl_xor(sm, 2);
                sm += __shfl_xor(sm, 4);
                sm += __shfl_xor(sm, 8);
                const float inv = 1.f / sm;
                w0[mts][r] = e0 * inv;
                w1[mts][r] = e1 * inv;
            }
        }
    }

    // ---- atw aliases own qs rows (dead now).  Zero, then write attn. ----
    short* atw = lds + b * 6480;   // 1088 shorts needed, 6480 available
    {
        int* az = reinterpret_cast<int*>(atw);
        #pragma unroll
        for (int i = 0; i < 9; ++i) {
            const int ix = lane + i * 64;
            if (ix < 544) az[ix] = 0;
        }
    }
    #pragma unroll
    for (int mts = 0; mts < 2; ++mts)
        #pragma unroll
        for (int r = 0; r < 4; ++r) {
            const int row = mts * 16 + lg * 4 + r;
            if (row < LL) {
                atw[row * 34 + lr]      = f2b(w0[mts][r]);
                atw[row * 34 + 16 + lr] = f2b(w1[mts][r]);   // lr>=4 writes 0
            }
        }
    // wave-private atw: ds-write -> ds-read ordering via lgkmcnt

    // ---- v = attn * xv ----
    bf16x8 va0 = *reinterpret_cast<const bf16x8*>(atw + lr * 34 + lg * 8);
    bf16x8 va1 = *reinterpret_cast<const bf16x8*>(atw + (16 + lr) * 34 + lg * 8);
    f32x4 z = {0.f, 0.f, 0.f, 0.f};
    f32x4 v0 = __builtin_amdgcn_mfma_f32_16x16x32_bf16(va0, bv, z, 0, 0, 0);
    f32x4 v1 = __builtin_amdgcn_mfma_f32_16x16x32_bf16(va1, bv, z, 0, 0, 0);
    #pragma unroll
    for (int r = 0; r < 4; ++r) {
        const int rowl = lg * 4 + r;
        const size_t o0 = (row0 + b * 20 + rowl) * 256 + n * 16 + lr;
        out1[o0] = v0[r];
        mhb[o0] = f2b(v0[r]);
        const int rowl1 = 16 + lg * 4 + r;
        if (rowl1 < LL) {
            const size_t o1 = (row0 + b * 20 + rowl1) * 256 + n * 16 + lr;
            out1[o1] = v1[r];
            mhb[o1] = f2b(v1[r]);
        }
    }
}

// ---------------------------------------------------------------------------
// gemm_ak: ak[32000][256] = mhb * kwb2^T.  m97 structure, K=256.
// ---------------------------------------------------------------------------
__global__ __launch_bounds__(256, 4) void gemm_ak(
    const short* __restrict__ mhb,   // [32000][256]
    const short* __restrict__ kwb,   // [256][256]
    short*       __restrict__ ak)    // [32000][256]
{
    const int nt0 = blockIdx.x * 128;
    const int mt0 = blockIdx.y * 128;
    const int tid = threadIdx.x, wave = tid >> 6, lane = tid & 63;
    const int lr = lane & 15, lg = lane >> 4;
    const int wm = wave & 1, wn = wave >> 1;

    __shared__ short sAB[8192];

    const int rA = tid >> 2, c = tid & 3;
    const short* aS0 = mhb + (size_t)(mt0 + rA) * 256 + c * 8;
    const short* aS1 = aS0 + (size_t)64 * 256;
    const short* bS0 = kwb + (size_t)(nt0 + rA) * 256 + c * 8;
    const short* bS1 = bS0 + (size_t)64 * 256;
    short* d0 = sAB + tid * 8;
    short* d1 = sAB + (tid + 256) * 8;
    short* d2 = sAB + (tid + 512) * 8;
    short* d3 = sAB + (tid + 768) * 8;

    f32x4 acc[4][4] = {};
    for (int ks = 0; ks < 8; ++ks) {
        __syncthreads();
        const int ko = ks * 32;
        gload16(aS0 + ko, d0);
        gload16(aS1 + ko, d1);
        gload16(bS0 + ko, d2);
        gload16(bS1 + ko, d3);
        __syncthreads();
        bf16x8 af[4], bfr[4];
        #pragma unroll
        for (int i = 0; i < 4; ++i)
            af[i] = *reinterpret_cast<const bf16x8*>(sAB + (wm * 64 + i * 16 + lr) * 32 + lg * 8);
        #pragma unroll
        for (int j = 0; j < 4; ++j)
            bfr[j] = *reinterpret_cast<const bf16x8*>(sAB + 4096 + (wn * 64 + j * 16 + lr) * 32 + lg * 8);
        #pragma unroll
        for (int i = 0; i < 4; ++i)
            #pragma unroll
            for (int j = 0; j < 4; ++j)
                acc[i][j] = __builtin_amdgcn_mfma_f32_16x16x32_bf16(af[i], bfr[j], acc[i][j], 0, 0, 0);
    }

    #pragma unroll
    for (int i = 0; i < 4; ++i)
        #pragma unroll
        for (int j = 0; j < 4; ++j)
            #pragma unroll
            for (int r = 0; r < 4; ++r)
                ak[(size_t)(mt0 + wm * 64 + i * 16 + lg * 4 + r) * 256
                   + nt0 + wn * 64 + j * 16 + lr] = f2b(acc[i][j][r]);
}

// ---------------------------------------------------------------------------
// pool_light: per bs — tanh/dot reduce, softmax, weighted sum.
// ---------------------------------------------------------------------------
__global__ __launch_bounds__(256) void pool_light(
    const short* __restrict__ ak,     // [32000][256] bf16
    const float* __restrict__ out1,   // mh fp32
    const float* __restrict__ keyB,   // [200]
    const float* __restrict__ query,  // [200]
    float*       __restrict__ out2)   // [NBS][256]
{
    const int bs = blockIdx.x;
    const int tid = threadIdx.x, wave = tid >> 6, lane = tid & 63;

    __shared__ float s2[LL];

    #pragma unroll
    for (int li = 0; li < 5; ++li) {
        const int l = wave * 5 + li;
        const short* ar = ak + ((size_t)bs * 20 + l) * 256;
        float acc = 0.f;
        #pragma unroll
        for (int it = 0; it < 4; ++it) {
            const int d = lane + it * 64;
            if (d < QD) {
                const float t = ftanh(b2f(ar[d]) + keyB[d]);
                acc = fmaf(query[d], t, acc);
            }
        }
        acc += __shfl_xor(acc, 32);
        acc += __shfl_xor(acc, 16);
        acc += __shfl_xor(acc, 8);
        acc += __shfl_xor(acc, 4);
        acc += __shfl_xor(acc, 2);
        acc += __shfl_xor(acc, 1);
        if (lane == 0) s2[l] = acc * 0.07071067811865475f;  // 1/sqrt(200)
    }
    __syncthreads();

    if (tid == 0) {
        float mx = -1e30f;
        #pragma unroll
        for (int l = 0; l < LL; ++l) mx = fmaxf(mx, s2[l]);
        float e[LL], sum = 0.f;
        #pragma unroll
        for (int l = 0; l < LL; ++l) { e[l] = __expf(s2[l] - mx); sum += e[l]; }
        const float inv = 1.f / sum;
        #pragma unroll
        for (int l = 0; l < LL; ++l) s2[l] = e[l] * inv;
    }
    __syncthreads();

    float o = 0.f;
    #pragma unroll
    for (int l = 0; l < LL; ++l)
        o = fmaf(s2[l], out1[((size_t)bs * 20 + l) * 256 + tid], o);
    out2[(size_t)bs * 256 + tid] = o;
}

// ===========================================================================
// FALLBACK (round-3, ~3.4 MB ws)
// ===========================================================================

#define XP 330
#define TP 42
#define AP 34

__global__ __launch_bounds__(1024) void transpose_qw(
    const float* __restrict__ qW, short* __restrict__ wqt)
{
    __shared__ float t[32][33];
    const int n = blockIdx.z;
    const int e0 = blockIdx.x * 32, f0 = blockIdx.y * 32;
    const int tx = threadIdx.x, ty = threadIdx.y;
    const int e = e0 + ty, f = f0 + tx;
    t[ty][tx] = (e < EE && f < EE) ? qW[(size_t)n * EE * EE + e * EE + f] : 0.f;
    __syncthreads();
    const int fo = f0 + ty, eo = e0 + tx;
    if (fo < 304)
        wqt[(size_t)n * 304 * 320 + fo * 320 + eo] = f2b(t[tx][ty]);
}

__global__ void conv_vw(const float* __restrict__ vW, short* __restrict__ wvt) {
    int idx = blockIdx.x * 256 + threadIdx.x;
    if (idx >= NH * VD * 320) return;
    int e = idx % 320;
    int v = (idx / 320) % VD;
    int n = idx / (320 * VD);
    wvt[idx] = (e < EE) ? f2b(vW[(size_t)n * EE * VD + e * VD + v]) : (short)0;
}

__global__ __launch_bounds__(512) void nrms_attn_mfma(
    const int*   __restrict__ news,
    const float* __restrict__ emb,
    const short* __restrict__ wqt,
    const float* __restrict__ qB,
    const short* __restrict__ wvt,
    const float* __restrict__ vB,
    float*       __restrict__ out1)
{
    const int bs   = blockIdx.x;
    const int tid  = threadIdx.x;
    const int wave = tid >> 6;
    const int lane = tid & 63;
    const int lr   = lane & 15;
    const int lg   = lane >> 4;

    __shared__ short xs[32][XP];
    __shared__ short xT[320][TP];
    __shared__ short qs[32][XP];
    __shared__ float sc[32][33];
    __shared__ short at[32][AP];

    {
        int* z = (int*)&xs[0][0];
        for (int i = tid; i < 32 * XP / 2; i += 512) z[i] = 0;
        z = (int*)&qs[0][0];
        for (int i = tid; i < 32 * XP / 2; i += 512) z[i] = 0;
        z = (int*)&xT[0][0];
        for (int i = tid; i < 320 * TP / 2; i += 512) z[i] = 0;
    }
    __syncthreads();

    for (int idx = tid; idx < LL * 75; idx += 512) {
        const int l = idx / 75, e4 = (idx % 75) * 4;
        const int row = news[bs * LL + l];
        const float4 v = *reinterpret_cast<const float4*>(emb + (size_t)row * EE + e4);
        const short b0 = f2b(v.x), b1 = f2b(v.y), b2 = f2b(v.z), b3 = f2b(v.w);
        xs[l][e4] = b0; xs[l][e4 + 1] = b1; xs[l][e4 + 2] = b2; xs[l][e4 + 3] = b3;
        xT[e4][l] = b0; xT[e4 + 1][l] = b1; xT[e4 + 2][l] = b2; xT[e4 + 3][l] = b3;
    }
    __syncthreads();

    for (int n = 0; n < NH; ++n) {
        const short* wq = wqt + (size_t)n * 304 * 320;

        for (int p = wave; p < 19; p += 8) {
            f32x4 acc0 = {0.f, 0.f, 0.f, 0.f};
            f32x4 acc1 = {0.f, 0.f, 0.f, 0.f};
            const short* a0p = &xs[lr][lg * 8];
            const short* a1p = &xs[16 + lr][lg * 8];
            const short* bp  = wq + (p * 16 + lr) * 320 + lg * 8;
            #pragma unroll
            for (int k = 0; k < 10; ++k) {
                bf16x8 b  = *reinterpret_cast<const bf16x8*>(bp + k * 32);
                bf16x8 a0 = *reinterpret_cast<const bf16x8*>(a0p + k * 32);
                bf16x8 a1 = *reinterpret_cast<const bf16x8*>(a1p + k * 32);
                acc0 = __builtin_amdgcn_mfma_f32_16x16x32_bf16(a0, b, acc0, 0, 0, 0);
                acc1 = __builtin_amdgcn_mfma_f32_16x16x32_bf16(a1, b, acc1, 0, 0, 0);
            }
            const int col = p * 16 + lr;
            const float bias = (col < EE) ? qB[n * EE + col] : 0.f;
            #pragma unroll
            for (int r = 0; r < 4; ++r) {
                qs[lg * 4 + r][col]      = f2b(acc0[r] + bias);
                qs[16 + lg * 4 + r][col] = f2b(acc1[r] + bias);
            }
        }
        __syncthreads();

        if (wave < 4) {
            const int mt = wave & 1, nt = wave >> 1;
            f32x4 acc = {0.f, 0.f, 0.f, 0.f};
            const short* ap = &qs[mt * 16 + lr][lg * 8];
            const short* bp = &xs[nt * 16 + lr][lg * 8];
            #pragma unroll
            for (int k = 0; k < 10; ++k) {
                bf16x8 a = *reinterpret_cast<const bf16x8*>(ap + k * 32);
                bf16x8 b = *reinterpret_cast<const bf16x8*>(bp + k * 32);
                acc = __builtin_amdgcn_mfma_f32_16x16x32_bf16(a, b, acc, 0, 0, 0);
            }
            #pragma unroll
            for (int r = 0; r < 4; ++r)
                sc[mt * 16 + lg * 4 + r][nt * 16 + lr] = acc[r] * 0.057735026918962584f;
        }
        __syncthreads();

        if (tid < LL) {
            float mx = -1e30f;
            #pragma unroll
            for (int m = 0; m < LL; ++m) mx = fmaxf(mx, sc[tid][m]);
            float ev[LL], sum = 0.f;
            #pragma unroll
            for (int m = 0; m < LL; ++m) { ev[m] = __expf(sc[tid][m] - mx); sum += ev[m]; }
            const float inv = 1.f / sum;
            #pragma unroll
            for (int m = 0; m < LL; ++m) at[tid][m] = f2b(ev[m] * inv);
            #pragma unroll
            for (int m = LL; m < 32; ++m) at[tid][m] = 0;
        } else if (tid < 32) {
            int* zr = (int*)&at[tid][0];
            #pragma unroll
            for (int m = 0; m < 16; ++m) zr[m] = 0;
        }
        __syncthreads();

        for (int p = wave; p < 19; p += 8) {
            bf16x8 b  = *reinterpret_cast<const bf16x8*>(&xT[p * 16 + lr][lg * 8]);
            bf16x8 a0 = *reinterpret_cast<const bf16x8*>(&at[lr][lg * 8]);
            bf16x8 a1 = *reinterpret_cast<const bf16x8*>(&at[16 + lr][lg * 8]);
            f32x4 z = {0.f, 0.f, 0.f, 0.f};
            f32x4 c0 = __builtin_amdgcn_mfma_f32_16x16x32_bf16(a0, b, z, 0, 0, 0);
            f32x4 c1 = __builtin_amdgcn_mfma_f32_16x16x32_bf16(a1, b, z, 0, 0, 0);
            const int col = p * 16 + lr;
            #pragma unroll
            for (int r = 0; r < 4; ++r) {
                qs[lg * 4 + r][col]      = f2b(c0[r]);
                qs[16 + lg * 4 + r][col] = f2b(c1[r]);
            }
        }
        __syncthreads();

        if (wave < 2) {
            const int mt = wave;
            f32x4 acc = {0.f, 0.f, 0.f, 0.f};
            const short* ap = &qs[mt * 16 + lr][lg * 8];
            const short* bp = wvt + (size_t)n * VD * 320 + lr * 320 + lg * 8;
            #pragma unroll
            for (int k = 0; k < 10; ++k) {
                bf16x8 a = *reinterpret_cast<const bf16x8*>(ap + k * 32);
                bf16x8 b = *reinterpret_cast<const bf16x8*>(bp + k * 32);
                acc = __builtin_amdgcn_mfma_f32_16x16x32_bf16(a, b, acc, 0, 0, 0);
            }
            #pragma unroll
            for (int r = 0; r < 4; ++r) {
                const int row = mt * 16 + lg * 4 + r;
                if (row < LL)
                    out1[((size_t)bs * LL + row) * HID + n * VD + lr] = acc[r] + vB[n * VD + lr];
            }
        }
        __syncthreads();
    }
}

__global__ __launch_bounds__(256) void nrms_pool_mfma(
    const float* __restrict__ out1,
    const short* __restrict__ kwb,    // [256][256] bf16 (rows >=200 zero)
    const float* __restrict__ keyB,
    const float* __restrict__ query,
    float*       __restrict__ out2)
{
    const int bs   = blockIdx.x;
    const int tid  = threadIdx.x;
    const int wave = tid >> 6;
    const int lane = tid & 63;
    const int lr   = lane & 15;
    const int lg   = lane >> 4;

    __shared__ float mh[LL][257];
    __shared__ short mhbl[32][264];
    __shared__ float s2p[32];

    for (int i = tid; i < 12 * 128; i += 256) {
        const int r = 20 + i / 128, c = (i % 128) * 2;
        *reinterpret_cast<int*>(&mhbl[r][c]) = 0;
    }
    if (tid < 32) s2p[tid] = 0.f;

    for (int idx = tid; idx < LL * 64; idx += 256) {
        const int l = idx >> 6, h4 = (idx & 63) * 4;
        const float4 v = *reinterpret_cast<const float4*>(out1 + ((size_t)bs * LL + l) * HID + h4);
        mh[l][h4] = v.x; mh[l][h4 + 1] = v.y; mh[l][h4 + 2] = v.z; mh[l][h4 + 3] = v.w;
        mhbl[l][h4] = f2b(v.x); mhbl[l][h4 + 1] = f2b(v.y);
        mhbl[l][h4 + 2] = f2b(v.z); mhbl[l][h4 + 3] = f2b(v.w);
    }
    __syncthreads();

    for (int t = wave; t < 26; t += 4) {
        const int mt = t & 1, nt = t >> 1;
        f32x4 acc = {0.f, 0.f, 0.f, 0.f};
        const short* ap = &mhbl[mt * 16 + lr][lg * 8];
        const short* bp = kwb + (nt * 16 + lr) * 256 + lg * 8;
        #pragma unroll
        for (int k = 0; k < 8; ++k) {
            bf16x8 a = *reinterpret_cast<const bf16x8*>(ap + k * 32);
            bf16x8 b = *reinterpret_cast<const bf16x8*>(bp + k * 32);
            acc = __builtin_amdgcn_mfma_f32_16x16x32_bf16(a, b, acc, 0, 0, 0);
        }
        const int d = nt * 16 + lr;
        const float qd = (d < QD) ? query[d] : 0.f;
        const float kb = (d < QD) ? keyB[d] : 0.f;
        float vals[4];
        #pragma unroll
        for (int r = 0; r < 4; ++r) vals[r] = qd * ftanh(acc[r] + kb);
        #pragma unroll
        for (int off = 1; off < 16; off <<= 1) {
            #pragma unroll
            for (int r = 0; r < 4; ++r) vals[r] += __shfl_xor(vals[r], off);
        }
        if (lr == 0) {
            #pragma unroll
            for (int r = 0; r < 4; ++r)
                atomicAdd(&s2p[mt * 16 + lg * 4 + r], vals[r]);
        }
    }
    __syncthreads();

    if (tid == 0) {
        float mx = -1e30f;
        #pragma unroll
        for (int l = 0; l < LL; ++l) mx = fmaxf(mx, s2p[l] * 0.07071067811865475f);
        float sum = 0.f;
        float e[LL];
        #pragma unroll
        for (int l = 0; l < LL; ++l) { e[l] = __expf(s2p[l] * 0.07071067811865475f - mx); sum += e[l]; }
        const float inv = 1.f / sum;
        #pragma unroll
        for (int l = 0; l < LL; ++l) s2p[l] = e[l] * inv;
    }
    __syncthreads();

    {
        const int h = tid;
        float acc = 0.f;
        #pragma unroll
        for (int l = 0; l < LL; ++l) acc = fmaf(s2p[l], mh[l][h], acc);
        out2[(size_t)bs * HID + h] = acc;
    }
}

// ===========================================================================

extern "C" void kernel_launch(void* const* d_in, const int* in_sizes, int n_in,
                              void* d_out, int out_size, void* d_ws, size_t ws_size,
                              hipStream_t stream) {
    const int*   news  = (const int*)d_in[0];
    const float* emb   = (const float*)d_in[1];
    const float* qW    = (const float*)d_in[2];
    const float* qB    = (const float*)d_in[3];
    const float* vW    = (const float*)d_in[4];
    const float* vB    = (const float*)d_in[5];
    const float* keyW  = (const float*)d_in[6];
    const float* keyB  = (const float*)d_in[7];
    const float* query = (const float*)d_in[8];

    float* out1 = (float*)d_out;            // news_embedding: 8192000 floats
    float* out2 = out1 + 8192000;           // news_repr: 409600 floats

    // base (shorts): Xb 10.24M, WqT 1.6384M, WvT 81920, xv 8.192M,
    //                kwb2 65536, mhb 8.192M, ak 8.192M  = 36,601,856 (73.2 MB)
    const size_t BASE_SH = 10240000ull + 1638400 + 81920 + 8192000
                         + 65536 + 8192000 + 8192000;
    const size_t BASE_B  = BASE_SH * 2;

    if (ws_size >= BASE_B) {
        short* Xb   = (short*)d_ws;
        short* WqT  = Xb + 10240000;
        short* WvT  = WqT + 1638400;
        short* xv   = WvT + 81920;
        short* kwb2 = xv + 8192000;
        short* mhb  = kwb2 + 65536;
        short* ak   = mhb + 8192000;

        hipLaunchKernelGGL(build_xb_lin, dim3(10000), dim3(256), 0, stream, news, emb, Xb);
        hipLaunchKernelGGL(build_wqt_lin, dim3(10, 10, 16), dim3(32, 32), 0, stream, qW, qB, WqT);
        hipLaunchKernelGGL(build_wvt, dim3(320), dim3(256), 0, stream, vW, vB, WvT);
        hipLaunchKernelGGL(conv_kw, dim3(256), dim3(256), 0, stream, keyW, kwb2);
        hipLaunchKernelGGL(gemm_xv, dim3(2, 250), dim3(256), 0, stream, Xb, WvT, xv);
        hipLaunchKernelGGL(qsv, dim3(400, 16), dim3(256), 0, stream,
                           Xb, WqT, xv, out1, mhb);
        hipLaunchKernelGGL(gemm_ak, dim3(2, 250), dim3(256), 0, stream, mhb, kwb2, ak);
        hipLaunchKernelGGL(pool_light, dim3(NBS), dim3(256), 0, stream,
                           ak, out1, keyB, query, out2);
    } else {
        short* wqt  = (short*)d_ws;
        short* wvt  = wqt + (size_t)NH * 304 * 320;
        short* kwb2 = wvt + (size_t)NH * VD * 320;

        hipLaunchKernelGGL(transpose_qw, dim3(10, 10, 16), dim3(32, 32), 0, stream, qW, wqt);
        hipLaunchKernelGGL(conv_vw, dim3(320), dim3(256), 0, stream, vW, wvt);
        hipLaunchKernelGGL(conv_kw, dim3(256), dim3(256), 0, stream, keyW, kwb2);
        hipLaunchKernelGGL(nrms_attn_mfma, dim3(NBS), dim3(512), 0, stream,
                           news, emb, wqt, qB, wvt, vB, out1);
        hipLaunchKernelGGL(nrms_pool_mfma, dim3(NBS), dim3(256), 0, stream,
                           out1, kwb2, keyB, query, out2);
    }
}

// Round 17
// 253.015 us; speedup vs baseline: 1.4402x; 1.0790x over previous
//
#include <hip/hip_runtime.h>
#include <math.h>

#define NBS 1600      // B*S
#define LL 20
#define EE 300
#define NH 16
#define VD 16
#define HID 256
#define QD 200

typedef short bf16x8 __attribute__((ext_vector_type(8)));
typedef float f32x4 __attribute__((ext_vector_type(4)));

__device__ __forceinline__ short f2b(float f) {
    union { float f; unsigned u; } c; c.f = f;
    unsigned r = (c.u + 0x7FFFu + ((c.u >> 16) & 1u)) >> 16;  // RNE
    return (short)r;
}

__device__ __forceinline__ float b2f(short s) {
    union { unsigned u; float f; } c; c.u = ((unsigned)(unsigned short)s) << 16;
    return c.f;
}

__device__ __forceinline__ float ftanh(float a) {
    a = fminf(fmaxf(a, -15.f), 15.f);
    float t = __expf(2.f * a);
    return (t - 1.f) / (t + 1.f);
}

__device__ __forceinline__ void gload16(const short* g, short* l) {
    __builtin_amdgcn_global_load_lds(
        (const __attribute__((address_space(1))) unsigned int*)g,
        (__attribute__((address_space(3))) unsigned int*)l, 16, 0, 0);
}

// ===========================================================================
// Build kernels
// ===========================================================================

// news/emb -> Xb bf16 [32000][320]; col300 = 1.0 (bias channel), 301..319 = 0
__global__ void build_xb_lin(const int* __restrict__ news, const float* __restrict__ emb,
                             short* __restrict__ Xb) {
    int idx = blockIdx.x * 256 + threadIdx.x;
    if (idx >= 32000 * 80) return;
    int i = idx / 80, e4 = (idx % 80) * 4;
    short4 o;
    if (e4 < 300) {
        const float4 v = *reinterpret_cast<const float4*>(emb + (size_t)news[i] * EE + e4);
        o.x = f2b(v.x); o.y = f2b(v.y); o.z = f2b(v.z); o.w = f2b(v.w);
    } else if (e4 == 300) {
        o.x = (short)0x3F80; o.y = 0; o.z = 0; o.w = 0;
    } else {
        o.x = o.y = o.z = o.w = 0;
    }
    *reinterpret_cast<short4*>(Xb + (size_t)i * 320 + e4) = o;
}

// Wq [n][e][f] -> WqT bf16 [5120 rows = n*320+f][320 cols = e], col300 = qB
__global__ __launch_bounds__(1024) void build_wqt_lin(
    const float* __restrict__ qW, const float* __restrict__ qB, short* __restrict__ WqT)
{
    __shared__ float t[32][33];
    const int n = blockIdx.z;
    const int e0 = blockIdx.x * 32, f0 = blockIdx.y * 32;
    const int tx = threadIdx.x, ty = threadIdx.y;
    const int e = e0 + ty, f = f0 + tx;
    t[ty][tx] = (e < EE && f < EE) ? qW[((size_t)n * EE + e) * EE + f] : 0.f;
    __syncthreads();
    const int fo = f0 + ty, eo = e0 + tx;
    float val;
    if (fo >= EE)      val = 0.f;
    else if (eo < EE)  val = t[tx][ty];
    else if (eo == EE) val = qB[n * EE + fo];
    else               val = 0.f;
    WqT[((size_t)n * 320 + fo) * 320 + eo] = f2b(val);
}

// Wv [n][e][v] -> WvT bf16 [256][320], col300 = vB
__global__ void build_wvt(const float* __restrict__ vW, const float* __restrict__ vB,
                          short* __restrict__ WvT) {
    int idx = blockIdx.x * 256 + threadIdx.x;
    if (idx >= 256 * 320) return;
    int c = idx / 320, e = idx % 320;
    int n = c >> 4, vd = c & 15;
    float val = (e < EE) ? vW[((size_t)n * EE + e) * VD + vd]
                         : (e == EE ? vB[n * VD + vd] : 0.f);
    WvT[idx] = f2b(val);
}

// keyW [200][256] fp32 -> bf16 kwb2 [256][256] (rows >=200 zero)
__global__ void conv_kw(const float* __restrict__ keyW, short* __restrict__ kwb) {
    int idx = blockIdx.x * 256 + threadIdx.x;
    if (idx >= 256 * 256) return;
    int d = idx >> 8;
    kwb[idx] = (d < QD) ? f2b(keyW[idx]) : (short)0;
}

// xv = Xb * WvT^T : [32000][256] bf16.  128x128 tile, 4 waves.
__global__ __launch_bounds__(256) void gemm_xv(
    const short* __restrict__ Xb, const short* __restrict__ WvT, short* __restrict__ xv)
{
    const int nt0 = blockIdx.x * 128;
    const size_t mt0 = (size_t)blockIdx.y * 128;
    const int tid = threadIdx.x, wave = tid >> 6, lane = tid & 63;
    const int lr = lane & 15, lg = lane >> 4;
    const int wm = wave & 1, wn = wave >> 1;

    __shared__ short As[128][68];
    __shared__ short Bs[128][68];
    f32x4 acc[4][4] = {};

    for (int ks = 0; ks < 5; ++ks) {
        __syncthreads();
        for (int u = 0; u < 4; ++u) {
            int idx = u * 256 + tid;
            int rr = idx >> 3, c8 = idx & 7;
            *reinterpret_cast<bf16x8*>(&As[rr][c8 * 8]) =
                *reinterpret_cast<const bf16x8*>(Xb + (mt0 + rr) * 320 + ks * 64 + c8 * 8);
            *reinterpret_cast<bf16x8*>(&Bs[rr][c8 * 8]) =
                *reinterpret_cast<const bf16x8*>(WvT + (size_t)(nt0 + rr) * 320 + ks * 64 + c8 * 8);
        }
        __syncthreads();
        #pragma unroll
        for (int kk = 0; kk < 2; ++kk) {
            bf16x8 af[4], bfv[4];
            #pragma unroll
            for (int f = 0; f < 4; ++f)
                af[f] = *reinterpret_cast<const bf16x8*>(&As[wm * 64 + f * 16 + lr][kk * 32 + lg * 8]);
            #pragma unroll
            for (int f = 0; f < 4; ++f)
                bfv[f] = *reinterpret_cast<const bf16x8*>(&Bs[wn * 64 + f * 16 + lr][kk * 32 + lg * 8]);
            #pragma unroll
            for (int i = 0; i < 4; ++i)
                #pragma unroll
                for (int j = 0; j < 4; ++j)
                    acc[i][j] = __builtin_amdgcn_mfma_f32_16x16x32_bf16(af[i], bfv[j], acc[i][j], 0, 0, 0);
        }
    }
    #pragma unroll
    for (int i = 0; i < 4; ++i)
        #pragma unroll
        for (int j = 0; j < 4; ++j)
            #pragma unroll
            for (int r = 0; r < 4; ++r)
                xv[(mt0 + wm * 64 + i * 16 + lg * 4 + r) * 256 + nt0 + wn * 64 + j * 16 + lr]
                    = f2b(acc[i][j][r]);
}

// ---------------------------------------------------------------------------
// qsv v4: fused q-GEMM + scores + softmax + v.  One block per (4 bs, head).
// grid (400,16), 256 thr, 4 waves.  GEMM now BK=64 (5 K-steps, 10 barriers
// instead of 20; 50 MFMA per step) with source-side XOR swizzle:
// LDS staging stays LINEAR (glds requirement); within each row of 64 shorts,
// 16B-seg slot p holds GLOBAL seg p^(row&7); frag reads use the same XOR
// -> per-bank access count = 8 = wave64 b128 minimum (conflict-free).
// Staging 25.6 KB aliased under qs [80][324] (51.8 KB total, unchanged).
// ---------------------------------------------------------------------------
__global__ __launch_bounds__(256, 2) void qsv(
    const short* __restrict__ Xb,    // [32000][320]
    const short* __restrict__ WqT,   // [5120][320]
    const short* __restrict__ xv,    // [32000][256]
    float*       __restrict__ out1,  // [32000][256]
    short*       __restrict__ mhb)   // [32000][256] bf16
{
    const int g = blockIdx.x;        // 4-bs group
    const int n = blockIdx.y;        // head
    const int tid = threadIdx.x, wave = tid >> 6, lane = tid & 63;
    const int lr = lane & 15, lg = lane >> 4;
    const size_t row0 = (size_t)g * 80;

    // [0,25600): staging (A [80][64] @0, B [320][64] @5120), source-swizzled
    // [0,25920): qs [80][324] after GEMM (aliases staging)
    // atw[b] aliases qs rows 20b.. (wave-private, dead after own scores)
    __shared__ short lds[25920];

    // staging: 3200 segs of 16B; thread t handles slots s = k*256+t, k=0..12
    // (k==12 only t<128).  Slot s = row*8+p; global seg loaded = p^(row&7).
    const short* gp[13];
    #pragma unroll
    for (int k = 0; k < 13; ++k) {
        const int s = k * 256 + tid;
        if (s < 640) {
            const int row = s >> 3, p = s & 7;
            gp[k] = Xb + (row0 + row) * 320 + (p ^ (row & 7)) * 8;
        } else if (s < 3200) {
            const int s2 = s - 640;
            const int row = s2 >> 3, p = s2 & 7;
            gp[k] = WqT + (size_t)(n * 320 + row) * 320 + (p ^ (row & 7)) * 8;
        } else {
            gp[k] = Xb;   // unused (k==12, tid>=128)
        }
    }

    // prefetch xv B-frag for v-phase (wave = bs)
    const int b = wave;
    bf16x8 bv;
    #pragma unroll
    for (int j = 0; j < 8; ++j) {
        int m = lg * 8 + j; if (m > 19) m = 19;   // attn cols >=20 are zero
        bv[j] = xv[(row0 + b * 20 + m) * 256 + n * 16 + lr];
    }

    const int sw = (lr & 7);   // frag-read XOR (row&7 == lr&7 for all frag rows)

    // ---- q-GEMM K-loop: 5 steps of BK=64 ----
    f32x4 acc[5][5] = {};
    for (int ks = 0; ks < 5; ++ks) {
        __syncthreads();                     // staging region free
        const int ko = ks * 64;
        #pragma unroll
        for (int k = 0; k < 12; ++k)
            gload16(gp[k] + ko, lds + (size_t)(k * 256 + tid) * 8);
        if (tid < 128)
            gload16(gp[12] + ko, lds + (size_t)(3072 + tid) * 8);
        __syncthreads();                     // glds drained
        #pragma unroll
        for (int sub = 0; sub < 2; ++sub) {
            bf16x8 af[5], bfr[5];
            #pragma unroll
            for (int i = 0; i < 5; ++i)
                af[i] = *reinterpret_cast<const bf16x8*>(
                    lds + (i * 16 + lr) * 64 + ((sub * 4 + lg) ^ sw) * 8);
            #pragma unroll
            for (int j = 0; j < 5; ++j)
                bfr[j] = *reinterpret_cast<const bf16x8*>(
                    lds + 5120 + (wave * 80 + j * 16 + lr) * 64 + ((sub * 4 + lg) ^ sw) * 8);
            #pragma unroll
            for (int i = 0; i < 5; ++i)
                #pragma unroll
                for (int j = 0; j < 5; ++j)
                    acc[i][j] = __builtin_amdgcn_mfma_f32_16x16x32_bf16(af[i], bfr[j], acc[i][j], 0, 0, 0);
        }
    }
    __syncthreads();   // staging reads done -> safe to overwrite with qs

    // ---- acc -> qs [80][324]; wave w owns cols [80w, 80w+80) ----
    #pragma unroll
    for (int i = 0; i < 5; ++i)
        #pragma unroll
        for (int j = 0; j < 5; ++j)
            #pragma unroll
            for (int r = 0; r < 4; ++r)
                lds[(i * 16 + lg * 4 + r) * 324 + wave * 80 + j * 16 + lr] = f2b(acc[i][j][r]);

    // ---- bulk-prefetch scores-phase X fragments (fly over the barrier) ----
    const int rA0 = b * 20 + lr;
    int rA1 = b * 20 + 16 + lr; if (rA1 > 79) rA1 = 79;
    bf16x8 xpre0[10], xpre1[10];
    #pragma unroll
    for (int ks = 0; ks < 10; ++ks) {
        xpre0[ks] = *reinterpret_cast<const bf16x8*>(Xb + (row0 + rA0) * 320 + ks * 32 + lg * 8);
        xpre1[ks] = *reinterpret_cast<const bf16x8*>(Xb + (row0 + rA1) * 320 + ks * 32 + lg * 8);
    }
    __syncthreads();   // qs complete

    // ---- scores + in-register softmax: wave = bs; results to registers ----
    float w0[2][4], w1[2][4];
    {
        f32x4 s[2][2] = {};
        #pragma unroll
        for (int ks = 0; ks < 10; ++ks) {
            const int kc = ks * 32 + lg * 8;
            bf16x8 a0 = *reinterpret_cast<const bf16x8*>(lds + rA0 * 324 + kc);
            bf16x8 a1 = *reinterpret_cast<const bf16x8*>(lds + rA1 * 324 + kc);
            s[0][0] = __builtin_amdgcn_mfma_f32_16x16x32_bf16(a0, xpre0[ks], s[0][0], 0, 0, 0);
            s[0][1] = __builtin_amdgcn_mfma_f32_16x16x32_bf16(a0, xpre1[ks], s[0][1], 0, 0, 0);
            s[1][0] = __builtin_amdgcn_mfma_f32_16x16x32_bf16(a1, xpre0[ks], s[1][0], 0, 0, 0);
            s[1][1] = __builtin_amdgcn_mfma_f32_16x16x32_bf16(a1, xpre1[ks], s[1][1], 0, 0, 0);
        }

        const float scl = 0.057735026918962584f;  // 1/sqrt(300)
        #pragma unroll
        for (int mts = 0; mts < 2; ++mts) {
            #pragma unroll
            for (int r = 0; r < 4; ++r) {
                float v0 = s[mts][0][r] * scl;
                float v1 = s[mts][1][r] * scl;
                float mx = (lr < 4) ? fmaxf(v0, v1) : v0;
                mx = fmaxf(mx, __shfl_xor(mx, 1));
                mx = fmaxf(mx, __shfl_xor(mx, 2));
                mx = fmaxf(mx, __shfl_xor(mx, 4));
                mx = fmaxf(mx, __shfl_xor(mx, 8));
                float e0 = __expf(v0 - mx);
                float e1 = (lr < 4) ? __expf(v1 - mx) : 0.f;
                float sm = e0 + e1;
                sm += __shfl_xor(sm, 1);
                sm += __shfl_xor(sm, 2);
                sm += __shfl_xor(sm, 4);
                sm += __shfl_xor(sm, 8);
                const float inv = 1.f / sm;
                w0[mts][r] = e0 * inv;
                w1[mts][r] = e1 * inv;
            }
        }
    }

    // ---- atw aliases own qs rows (dead now).  Zero, then write attn. ----
    short* atw = lds + b * 6480;   // 1088 shorts needed, 6480 available
    {
        int* az = reinterpret_cast<int*>(atw);
        #pragma unroll
        for (int i = 0; i < 9; ++i) {
            const int ix = lane + i * 64;
            if (ix < 544) az[ix] = 0;
        }
    }
    #pragma unroll
    for (int mts = 0; mts < 2; ++mts)
        #pragma unroll
        for (int r = 0; r < 4; ++r) {
            const int row = mts * 16 + lg * 4 + r;
            if (row < LL) {
                atw[row * 34 + lr]      = f2b(w0[mts][r]);
                atw[row * 34 + 16 + lr] = f2b(w1[mts][r]);   // lr>=4 writes 0
            }
        }
    // wave-private atw: ds-write -> ds-read ordering via lgkmcnt

    // ---- v = attn * xv ----
    bf16x8 va0 = *reinterpret_cast<const bf16x8*>(atw + lr * 34 + lg * 8);
    bf16x8 va1 = *reinterpret_cast<const bf16x8*>(atw + (16 + lr) * 34 + lg * 8);
    f32x4 z = {0.f, 0.f, 0.f, 0.f};
    f32x4 v0 = __builtin_amdgcn_mfma_f32_16x16x32_bf16(va0, bv, z, 0, 0, 0);
    f32x4 v1 = __builtin_amdgcn_mfma_f32_16x16x32_bf16(va1, bv, z, 0, 0, 0);
    #pragma unroll
    for (int r = 0; r < 4; ++r) {
        const int rowl = lg * 4 + r;
        const size_t o0 = (row0 + b * 20 + rowl) * 256 + n * 16 + lr;
        out1[o0] = v0[r];
        mhb[o0] = f2b(v0[r]);
        const int rowl1 = 16 + lg * 4 + r;
        if (rowl1 < LL) {
            const size_t o1 = (row0 + b * 20 + rowl1) * 256 + n * 16 + lr;
            out1[o1] = v1[r];
            mhb[o1] = f2b(v1[r]);
        }
    }
}

// ---------------------------------------------------------------------------
// gemm_ak: ak[32000][256] = mhb * kwb2^T.  m97 structure, K=256.
// ---------------------------------------------------------------------------
__global__ __launch_bounds__(256, 4) void gemm_ak(
    const short* __restrict__ mhb,   // [32000][256]
    const short* __restrict__ kwb,   // [256][256]
    short*       __restrict__ ak)    // [32000][256]
{
    const int nt0 = blockIdx.x * 128;
    const int mt0 = blockIdx.y * 128;
    const int tid = threadIdx.x, wave = tid >> 6, lane = tid & 63;
    const int lr = lane & 15, lg = lane >> 4;
    const int wm = wave & 1, wn = wave >> 1;

    __shared__ short sAB[8192];

    const int rA = tid >> 2, c = tid & 3;
    const short* aS0 = mhb + (size_t)(mt0 + rA) * 256 + c * 8;
    const short* aS1 = aS0 + (size_t)64 * 256;
    const short* bS0 = kwb + (size_t)(nt0 + rA) * 256 + c * 8;
    const short* bS1 = bS0 + (size_t)64 * 256;
    short* d0 = sAB + tid * 8;
    short* d1 = sAB + (tid + 256) * 8;
    short* d2 = sAB + (tid + 512) * 8;
    short* d3 = sAB + (tid + 768) * 8;

    f32x4 acc[4][4] = {};
    for (int ks = 0; ks < 8; ++ks) {
        __syncthreads();
        const int ko = ks * 32;
        gload16(aS0 + ko, d0);
        gload16(aS1 + ko, d1);
        gload16(bS0 + ko, d2);
        gload16(bS1 + ko, d3);
        __syncthreads();
        bf16x8 af[4], bfr[4];
        #pragma unroll
        for (int i = 0; i < 4; ++i)
            af[i] = *reinterpret_cast<const bf16x8*>(sAB + (wm * 64 + i * 16 + lr) * 32 + lg * 8);
        #pragma unroll
        for (int j = 0; j < 4; ++j)
            bfr[j] = *reinterpret_cast<const bf16x8*>(sAB + 4096 + (wn * 64 + j * 16 + lr) * 32 + lg * 8);
        #pragma unroll
        for (int i = 0; i < 4; ++i)
            #pragma unroll
            for (int j = 0; j < 4; ++j)
                acc[i][j] = __builtin_amdgcn_mfma_f32_16x16x32_bf16(af[i], bfr[j], acc[i][j], 0, 0, 0);
    }

    #pragma unroll
    for (int i = 0; i < 4; ++i)
        #pragma unroll
        for (int j = 0; j < 4; ++j)
            #pragma unroll
            for (int r = 0; r < 4; ++r)
                ak[(size_t)(mt0 + wm * 64 + i * 16 + lg * 4 + r) * 256
                   + nt0 + wn * 64 + j * 16 + lr] = f2b(acc[i][j][r]);
}

// ---------------------------------------------------------------------------
// pool_light: per bs — tanh/dot reduce, softmax, weighted sum.
// ---------------------------------------------------------------------------
__global__ __launch_bounds__(256) void pool_light(
    const short* __restrict__ ak,     // [32000][256] bf16
    const float* __restrict__ out1,   // mh fp32
    const float* __restrict__ keyB,   // [200]
    const float* __restrict__ query,  // [200]
    float*       __restrict__ out2)   // [NBS][256]
{
    const int bs = blockIdx.x;
    const int tid = threadIdx.x, wave = tid >> 6, lane = tid & 63;

    __shared__ float s2[LL];

    #pragma unroll
    for (int li = 0; li < 5; ++li) {
        const int l = wave * 5 + li;
        const short* ar = ak + ((size_t)bs * 20 + l) * 256;
        float acc = 0.f;
        #pragma unroll
        for (int it = 0; it < 4; ++it) {
            const int d = lane + it * 64;
            if (d < QD) {
                const float t = ftanh(b2f(ar[d]) + keyB[d]);
                acc = fmaf(query[d], t, acc);
            }
        }
        acc += __shfl_xor(acc, 32);
        acc += __shfl_xor(acc, 16);
        acc += __shfl_xor(acc, 8);
        acc += __shfl_xor(acc, 4);
        acc += __shfl_xor(acc, 2);
        acc += __shfl_xor(acc, 1);
        if (lane == 0) s2[l] = acc * 0.07071067811865475f;  // 1/sqrt(200)
    }
    __syncthreads();

    if (tid == 0) {
        float mx = -1e30f;
        #pragma unroll
        for (int l = 0; l < LL; ++l) mx = fmaxf(mx, s2[l]);
        float e[LL], sum = 0.f;
        #pragma unroll
        for (int l = 0; l < LL; ++l) { e[l] = __expf(s2[l] - mx); sum += e[l]; }
        const float inv = 1.f / sum;
        #pragma unroll
        for (int l = 0; l < LL; ++l) s2[l] = e[l] * inv;
    }
    __syncthreads();

    float o = 0.f;
    #pragma unroll
    for (int l = 0; l < LL; ++l)
        o = fmaf(s2[l], out1[((size_t)bs * 20 + l) * 256 + tid], o);
    out2[(size_t)bs * 256 + tid] = o;
}

// ===========================================================================
// FALLBACK (round-3, ~3.4 MB ws)
// ===========================================================================

#define XP 330
#define TP 42
#define AP 34

__global__ __launch_bounds__(1024) void transpose_qw(
    const float* __restrict__ qW, short* __restrict__ wqt)
{
    __shared__ float t[32][33];
    const int n = blockIdx.z;
    const int e0 = blockIdx.x * 32, f0 = blockIdx.y * 32;
    const int tx = threadIdx.x, ty = threadIdx.y;
    const int e = e0 + ty, f = f0 + tx;
    t[ty][tx] = (e < EE && f < EE) ? qW[(size_t)n * EE * EE + e * EE + f] : 0.f;
    __syncthreads();
    const int fo = f0 + ty, eo = e0 + tx;
    if (fo < 304)
        wqt[(size_t)n * 304 * 320 + fo * 320 + eo] = f2b(t[tx][ty]);
}

__global__ void conv_vw(const float* __restrict__ vW, short* __restrict__ wvt) {
    int idx = blockIdx.x * 256 + threadIdx.x;
    if (idx >= NH * VD * 320) return;
    int e = idx % 320;
    int v = (idx / 320) % VD;
    int n = idx / (320 * VD);
    wvt[idx] = (e < EE) ? f2b(vW[(size_t)n * EE * VD + e * VD + v]) : (short)0;
}

__global__ __launch_bounds__(512) void nrms_attn_mfma(
    const int*   __restrict__ news,
    const float* __restrict__ emb,
    const short* __restrict__ wqt,
    const float* __restrict__ qB,
    const short* __restrict__ wvt,
    const float* __restrict__ vB,
    float*       __restrict__ out1)
{
    const int bs   = blockIdx.x;
    const int tid  = threadIdx.x;
    const int wave = tid >> 6;
    const int lane = tid & 63;
    const int lr   = lane & 15;
    const int lg   = lane >> 4;

    __shared__ short xs[32][XP];
    __shared__ short xT[320][TP];
    __shared__ short qs[32][XP];
    __shared__ float sc[32][33];
    __shared__ short at[32][AP];

    {
        int* z = (int*)&xs[0][0];
        for (int i = tid; i < 32 * XP / 2; i += 512) z[i] = 0;
        z = (int*)&qs[0][0];
        for (int i = tid; i < 32 * XP / 2; i += 512) z[i] = 0;
        z = (int*)&xT[0][0];
        for (int i = tid; i < 320 * TP / 2; i += 512) z[i] = 0;
    }
    __syncthreads();

    for (int idx = tid; idx < LL * 75; idx += 512) {
        const int l = idx / 75, e4 = (idx % 75) * 4;
        const int row = news[bs * LL + l];
        const float4 v = *reinterpret_cast<const float4*>(emb + (size_t)row * EE + e4);
        const short b0 = f2b(v.x), b1 = f2b(v.y), b2 = f2b(v.z), b3 = f2b(v.w);
        xs[l][e4] = b0; xs[l][e4 + 1] = b1; xs[l][e4 + 2] = b2; xs[l][e4 + 3] = b3;
        xT[e4][l] = b0; xT[e4 + 1][l] = b1; xT[e4 + 2][l] = b2; xT[e4 + 3][l] = b3;
    }
    __syncthreads();

    for (int n = 0; n < NH; ++n) {
        const short* wq = wqt + (size_t)n * 304 * 320;

        for (int p = wave; p < 19; p += 8) {
            f32x4 acc0 = {0.f, 0.f, 0.f, 0.f};
            f32x4 acc1 = {0.f, 0.f, 0.f, 0.f};
            const short* a0p = &xs[lr][lg * 8];
            const short* a1p = &xs[16 + lr][lg * 8];
            const short* bp  = wq + (p * 16 + lr) * 320 + lg * 8;
            #pragma unroll
            for (int k = 0; k < 10; ++k) {
                bf16x8 b  = *reinterpret_cast<const bf16x8*>(bp + k * 32);
                bf16x8 a0 = *reinterpret_cast<const bf16x8*>(a0p + k * 32);
                bf16x8 a1 = *reinterpret_cast<const bf16x8*>(a1p + k * 32);
                acc0 = __builtin_amdgcn_mfma_f32_16x16x32_bf16(a0, b, acc0, 0, 0, 0);
                acc1 = __builtin_amdgcn_mfma_f32_16x16x32_bf16(a1, b, acc1, 0, 0, 0);
            }
            const int col = p * 16 + lr;
            const float bias = (col < EE) ? qB[n * EE + col] : 0.f;
            #pragma unroll
            for (int r = 0; r < 4; ++r) {
                qs[lg * 4 + r][col]      = f2b(acc0[r] + bias);
                qs[16 + lg * 4 + r][col] = f2b(acc1[r] + bias);
            }
        }
        __syncthreads();

        if (wave < 4) {
            const int mt = wave & 1, nt = wave >> 1;
            f32x4 acc = {0.f, 0.f, 0.f, 0.f};
            const short* ap = &qs[mt * 16 + lr][lg * 8];
            const short* bp = &xs[nt * 16 + lr][lg * 8];
            #pragma unroll
            for (int k = 0; k < 10; ++k) {
                bf16x8 a = *reinterpret_cast<const bf16x8*>(ap + k * 32);
                bf16x8 b = *reinterpret_cast<const bf16x8*>(bp + k * 32);
                acc = __builtin_amdgcn_mfma_f32_16x16x32_bf16(a, b, acc, 0, 0, 0);
            }
            #pragma unroll
            for (int r = 0; r < 4; ++r)
                sc[mt * 16 + lg * 4 + r][nt * 16 + lr] = acc[r] * 0.057735026918962584f;
        }
        __syncthreads();

        if (tid < LL) {
            float mx = -1e30f;
            #pragma unroll
            for (int m = 0; m < LL; ++m) mx = fmaxf(mx, sc[tid][m]);
            float ev[LL], sum = 0.f;
            #pragma unroll
            for (int m = 0; m < LL; ++m) { ev[m] = __expf(sc[tid][m] - mx); sum += ev[m]; }
            const float inv = 1.f / sum;
            #pragma unroll
            for (int m = 0; m < LL; ++m) at[tid][m] = f2b(ev[m] * inv);
            #pragma unroll
            for (int m = LL; m < 32; ++m) at[tid][m] = 0;
        } else if (tid < 32) {
            int* zr = (int*)&at[tid][0];
            #pragma unroll
            for (int m = 0; m < 16; ++m) zr[m] = 0;
        }
        __syncthreads();

        for (int p = wave; p < 19; p += 8) {
            bf16x8 b  = *reinterpret_cast<const bf16x8*>(&xT[p * 16 + lr][lg * 8]);
            bf16x8 a0 = *reinterpret_cast<const bf16x8*>(&at[lr][lg * 8]);
            bf16x8 a1 = *reinterpret_cast<const bf16x8*>(&at[16 + lr][lg * 8]);
            f32x4 z = {0.f, 0.f, 0.f, 0.f};
            f32x4 c0 = __builtin_amdgcn_mfma_f32_16x16x32_bf16(a0, b, z, 0, 0, 0);
            f32x4 c1 = __builtin_amdgcn_mfma_f32_16x16x32_bf16(a1, b, z, 0, 0, 0);
            const int col = p * 16 + lr;
            #pragma unroll
            for (int r = 0; r < 4; ++r) {
                qs[lg * 4 + r][col]      = f2b(c0[r]);
                qs[16 + lg * 4 + r][col] = f2b(c1[r]);
            }
        }
        __syncthreads();

        if (wave < 2) {
            const int mt = wave;
            f32x4 acc = {0.f, 0.f, 0.f, 0.f};
            const short* ap = &qs[mt * 16 + lr][lg * 8];
            const short* bp = wvt + (size_t)n * VD * 320 + lr * 320 + lg * 8;
            #pragma unroll
            for (int k = 0; k < 10; ++k) {
                bf16x8 a = *reinterpret_cast<const bf16x8*>(ap + k * 32);
                bf16x8 b = *reinterpret_cast<const bf16x8*>(bp + k * 32);
                acc = __builtin_amdgcn_mfma_f32_16x16x32_bf16(a, b, acc, 0, 0, 0);
            }
            #pragma unroll
            for (int r = 0; r < 4; ++r) {
                const int row = mt * 16 + lg * 4 + r;
                if (row < LL)
                    out1[((size_t)bs * LL + row) * HID + n * VD + lr] = acc[r] + vB[n * VD + lr];
            }
        }
        __syncthreads();
    }
}

__global__ __launch_bounds__(256) void nrms_pool_mfma(
    const float* __restrict__ out1,
    const short* __restrict__ kwb,    // [256][256] bf16 (rows >=200 zero)
    const float* __restrict__ keyB,
    const float* __restrict__ query,
    float*       __restrict__ out2)
{
    const int bs   = blockIdx.x;
    const int tid  = threadIdx.x;
    const int wave = tid >> 6;
    const int lane = tid & 63;
    const int lr   = lane & 15;
    const int lg   = lane >> 4;

    __shared__ float mh[LL][257];
    __shared__ short mhbl[32][264];
    __shared__ float s2p[32];

    for (int i = tid; i < 12 * 128; i += 256) {
        const int r = 20 + i / 128, c = (i % 128) * 2;
        *reinterpret_cast<int*>(&mhbl[r][c]) = 0;
    }
    if (tid < 32) s2p[tid] = 0.f;

    for (int idx = tid; idx < LL * 64; idx += 256) {
        const int l = idx >> 6, h4 = (idx & 63) * 4;
        const float4 v = *reinterpret_cast<const float4*>(out1 + ((size_t)bs * LL + l) * HID + h4);
        mh[l][h4] = v.x; mh[l][h4 + 1] = v.y; mh[l][h4 + 2] = v.z; mh[l][h4 + 3] = v.w;
        mhbl[l][h4] = f2b(v.x); mhbl[l][h4 + 1] = f2b(v.y);
        mhbl[l][h4 + 2] = f2b(v.z); mhbl[l][h4 + 3] = f2b(v.w);
    }
    __syncthreads();

    for (int t = wave; t < 26; t += 4) {
        const int mt = t & 1, nt = t >> 1;
        f32x4 acc = {0.f, 0.f, 0.f, 0.f};
        const short* ap = &mhbl[mt * 16 + lr][lg * 8];
        const short* bp = kwb + (nt * 16 + lr) * 256 + lg * 8;
        #pragma unroll
        for (int k = 0; k < 8; ++k) {
            bf16x8 a = *reinterpret_cast<const bf16x8*>(ap + k * 32);
            bf16x8 b = *reinterpret_cast<const bf16x8*>(bp + k * 32);
            acc = __builtin_amdgcn_mfma_f32_16x16x32_bf16(a, b, acc, 0, 0, 0);
        }
        const int d = nt * 16 + lr;
        const float qd = (d < QD) ? query[d] : 0.f;
        const float kb = (d < QD) ? keyB[d] : 0.f;
        float vals[4];
        #pragma unroll
        for (int r = 0; r < 4; ++r) vals[r] = qd * ftanh(acc[r] + kb);
        #pragma unroll
        for (int off = 1; off < 16; off <<= 1) {
            #pragma unroll
            for (int r = 0; r < 4; ++r) vals[r] += __shfl_xor(vals[r], off);
        }
        if (lr == 0) {
            #pragma unroll
            for (int r = 0; r < 4; ++r)
                atomicAdd(&s2p[mt * 16 + lg * 4 + r], vals[r]);
        }
    }
    __syncthreads();

    if (tid == 0) {
        float mx = -1e30f;
        #pragma unroll
        for (int l = 0; l < LL; ++l) mx = fmaxf(mx, s2p[l] * 0.07071067811865475f);
        float sum = 0.f;
        float e[LL];
        #pragma unroll
        for (int l = 0; l < LL; ++l) { e[l] = __expf(s2p[l] * 0.07071067811865475f - mx); sum += e[l]; }
        const float inv = 1.f / sum;
        #pragma unroll
        for (int l = 0; l < LL; ++l) s2p[l] = e[l] * inv;
    }
    __syncthreads();

    {
        const int h = tid;
        float acc = 0.f;
        #pragma unroll
        for (int l = 0; l < LL; ++l) acc = fmaf(s2p[l], mh[l][h], acc);
        out2[(size_t)bs * HID + h] = acc;
    }
}

// ===========================================================================

extern "C" void kernel_launch(void* const* d_in, const int* in_sizes, int n_in,
                              void* d_out, int out_size, void* d_ws, size_t ws_size,
                              hipStream_t stream) {
    const int*   news  = (const int*)d_in[0];
    const float* emb   = (const float*)d_in[1];
    const float* qW    = (const float*)d_in[2];
    const float* qB    = (const float*)d_in[3];
    const float* vW    = (const float*)d_in[4];
    const float* vB    = (const float*)d_in[5];
    const float* keyW  = (const float*)d_in[6];
    const float* keyB  = (const float*)d_in[7];
    const float* query = (const float*)d_in[8];

    float* out1 = (float*)d_out;            // news_embedding: 8192000 floats
    float* out2 = out1 + 8192000;           // news_repr: 409600 floats

    // base (shorts): Xb 10.24M, WqT 1.6384M, WvT 81920, xv 8.192M,
    //                kwb2 65536, mhb 8.192M, ak 8.192M  = 36,601,856 (73.2 MB)
    const size_t BASE_SH = 10240000ull + 1638400 + 81920 + 8192000
                         + 65536 + 8192000 + 8192000;
    const size_t BASE_B  = BASE_SH * 2;

    if (ws_size >= BASE_B) {
        short* Xb   = (short*)d_ws;
        short* WqT  = Xb + 10240000;
        short* WvT  = WqT + 1638400;
        short* xv   = WvT + 81920;
        short* kwb2 = xv + 8192000;
        short* mhb  = kwb2 + 65536;
        short* ak   = mhb + 8192000;

        hipLaunchKernelGGL(build_xb_lin, dim3(10000), dim3(256), 0, stream, news, emb, Xb);
        hipLaunchKernelGGL(build_wqt_lin, dim3(10, 10, 16), dim3(32, 32), 0, stream, qW, qB, WqT);
        hipLaunchKernelGGL(build_wvt, dim3(320), dim3(256), 0, stream, vW, vB, WvT);
        hipLaunchKernelGGL(conv_kw, dim3(256), dim3(256), 0, stream, keyW, kwb2);
        hipLaunchKernelGGL(gemm_xv, dim3(2, 250), dim3(256), 0, stream, Xb, WvT, xv);
        hipLaunchKernelGGL(qsv, dim3(400, 16), dim3(256), 0, stream,
                           Xb, WqT, xv, out1, mhb);
        hipLaunchKernelGGL(gemm_ak, dim3(2, 250), dim3(256), 0, stream, mhb, kwb2, ak);
        hipLaunchKernelGGL(pool_light, dim3(NBS), dim3(256), 0, stream,
                           ak, out1, keyB, query, out2);
    } else {
        short* wqt  = (short*)d_ws;
        short* wvt  = wqt + (size_t)NH * 304 * 320;
        short* kwb2 = wvt + (size_t)NH * VD * 320;

        hipLaunchKernelGGL(transpose_qw, dim3(10, 10, 16), dim3(32, 32), 0, stream, qW, wqt);
        hipLaunchKernelGGL(conv_vw, dim3(320), dim3(256), 0, stream, vW, wvt);
        hipLaunchKernelGGL(conv_kw, dim3(256), dim3(256), 0, stream, keyW, kwb2);
        hipLaunchKernelGGL(nrms_attn_mfma, dim3(NBS), dim3(512), 0, stream,
                           news, emb, wqt, qB, wvt, vB, out1);
        hipLaunchKernelGGL(nrms_pool_mfma, dim3(NBS), dim3(256), 0, stream,
                           out1, kwb2, keyB, query, out2);
    }
}

// Round 18
// 249.027 us; speedup vs baseline: 1.4633x; 1.0160x over previous
//
#include <hip/hip_runtime.h>
#include <math.h>

#define NBS 1600      // B*S
#define LL 20
#define EE 300
#define NH 16
#define VD 16
#define HID 256
#define QD 200

typedef short bf16x8 __attribute__((ext_vector_type(8)));
typedef float f32x4 __attribute__((ext_vector_type(4)));

__device__ __forceinline__ short f2b(float f) {
    union { float f; unsigned u; } c; c.f = f;
    unsigned r = (c.u + 0x7FFFu + ((c.u >> 16) & 1u)) >> 16;  // RNE
    return (short)r;
}

__device__ __forceinline__ float b2f(short s) {
    union { unsigned u; float f; } c; c.u = ((unsigned)(unsigned short)s) << 16;
    return c.f;
}

__device__ __forceinline__ float ftanh(float a) {
    a = fminf(fmaxf(a, -15.f), 15.f);
    float t = __expf(2.f * a);
    return (t - 1.f) / (t + 1.f);
}

__device__ __forceinline__ void gload16(const short* g, short* l) {
    __builtin_amdgcn_global_load_lds(
        (const __attribute__((address_space(1))) unsigned int*)g,
        (__attribute__((address_space(3))) unsigned int*)l, 16, 0, 0);
}

// ===========================================================================
// Build kernels
// ===========================================================================

// Fused small builds: Xb gather+pad, WvT, kwb2.
//  idx < 2,560,000          : Xb short4 seg (32000*80)
//  next 81,920              : WvT element
//  next 65,536              : kwb2 element
__global__ void build_all(const int* __restrict__ news, const float* __restrict__ emb,
                          const float* __restrict__ vW, const float* __restrict__ vB,
                          const float* __restrict__ keyW,
                          short* __restrict__ Xb, short* __restrict__ WvT,
                          short* __restrict__ kwb) {
    int idx = blockIdx.x * 256 + threadIdx.x;
    if (idx < 2560000) {
        int i = idx / 80, e4 = (idx % 80) * 4;
        short4 o;
        if (e4 < 300) {
            const float4 v = *reinterpret_cast<const float4*>(emb + (size_t)news[i] * EE + e4);
            o.x = f2b(v.x); o.y = f2b(v.y); o.z = f2b(v.z); o.w = f2b(v.w);
        } else if (e4 == 300) {
            o.x = (short)0x3F80; o.y = 0; o.z = 0; o.w = 0;
        } else {
            o.x = o.y = o.z = o.w = 0;
        }
        *reinterpret_cast<short4*>(Xb + (size_t)i * 320 + e4) = o;
        return;
    }
    idx -= 2560000;
    if (idx < 81920) {
        int c = idx / 320, e = idx % 320;
        int n = c >> 4, vd = c & 15;
        float val = (e < EE) ? vW[((size_t)n * EE + e) * VD + vd]
                             : (e == EE ? vB[n * VD + vd] : 0.f);
        WvT[idx] = f2b(val);
        return;
    }
    idx -= 81920;
    if (idx < 65536) {
        int d = idx >> 8;
        kwb[idx] = (d < QD) ? f2b(keyW[idx]) : (short)0;
    }
}

// Wq [n][e][f] -> WqT bf16 [5120 rows = n*320+f][320 cols = e], col300 = qB
__global__ __launch_bounds__(1024) void build_wqt_lin(
    const float* __restrict__ qW, const float* __restrict__ qB, short* __restrict__ WqT)
{
    __shared__ float t[32][33];
    const int n = blockIdx.z;
    const int e0 = blockIdx.x * 32, f0 = blockIdx.y * 32;
    const int tx = threadIdx.x, ty = threadIdx.y;
    const int e = e0 + ty, f = f0 + tx;
    t[ty][tx] = (e < EE && f < EE) ? qW[((size_t)n * EE + e) * EE + f] : 0.f;
    __syncthreads();
    const int fo = f0 + ty, eo = e0 + tx;
    float val;
    if (fo >= EE)      val = 0.f;
    else if (eo < EE)  val = t[tx][ty];
    else if (eo == EE) val = qB[n * EE + fo];
    else               val = 0.f;
    WqT[((size_t)n * 320 + fo) * 320 + eo] = f2b(val);
}

// xv = Xb * WvT^T : [32000][256] bf16.  128x128 tile, 4 waves.
__global__ __launch_bounds__(256) void gemm_xv(
    const short* __restrict__ Xb, const short* __restrict__ WvT, short* __restrict__ xv)
{
    const int nt0 = blockIdx.x * 128;
    const size_t mt0 = (size_t)blockIdx.y * 128;
    const int tid = threadIdx.x, wave = tid >> 6, lane = tid & 63;
    const int lr = lane & 15, lg = lane >> 4;
    const int wm = wave & 1, wn = wave >> 1;

    __shared__ short As[128][68];
    __shared__ short Bs[128][68];
    f32x4 acc[4][4] = {};

    for (int ks = 0; ks < 5; ++ks) {
        __syncthreads();
        for (int u = 0; u < 4; ++u) {
            int idx = u * 256 + tid;
            int rr = idx >> 3, c8 = idx & 7;
            *reinterpret_cast<bf16x8*>(&As[rr][c8 * 8]) =
                *reinterpret_cast<const bf16x8*>(Xb + (mt0 + rr) * 320 + ks * 64 + c8 * 8);
            *reinterpret_cast<bf16x8*>(&Bs[rr][c8 * 8]) =
                *reinterpret_cast<const bf16x8*>(WvT + (size_t)(nt0 + rr) * 320 + ks * 64 + c8 * 8);
        }
        __syncthreads();
        #pragma unroll
        for (int kk = 0; kk < 2; ++kk) {
            bf16x8 af[4], bfv[4];
            #pragma unroll
            for (int f = 0; f < 4; ++f)
                af[f] = *reinterpret_cast<const bf16x8*>(&As[wm * 64 + f * 16 + lr][kk * 32 + lg * 8]);
            #pragma unroll
            for (int f = 0; f < 4; ++f)
                bfv[f] = *reinterpret_cast<const bf16x8*>(&Bs[wn * 64 + f * 16 + lr][kk * 32 + lg * 8]);
            #pragma unroll
            for (int i = 0; i < 4; ++i)
                #pragma unroll
                for (int j = 0; j < 4; ++j)
                    acc[i][j] = __builtin_amdgcn_mfma_f32_16x16x32_bf16(af[i], bfv[j], acc[i][j], 0, 0, 0);
        }
    }
    #pragma unroll
    for (int i = 0; i < 4; ++i)
        #pragma unroll
        for (int j = 0; j < 4; ++j)
            #pragma unroll
            for (int r = 0; r < 4; ++r)
                xv[(mt0 + wm * 64 + i * 16 + lg * 4 + r) * 256 + nt0 + wn * 64 + j * 16 + lr]
                    = f2b(acc[i][j][r]);
}

// ---------------------------------------------------------------------------
// qsv v4 (unchanged from r17): fused q-GEMM + scores + softmax + v.
// BK=64, source-side XOR swizzle, LDS 51.8 KB.
// ---------------------------------------------------------------------------
__global__ __launch_bounds__(256, 2) void qsv(
    const short* __restrict__ Xb,    // [32000][320]
    const short* __restrict__ WqT,   // [5120][320]
    const short* __restrict__ xv,    // [32000][256]
    float*       __restrict__ out1,  // [32000][256]
    short*       __restrict__ mhb)   // [32000][256] bf16
{
    const int g = blockIdx.x;        // 4-bs group
    const int n = blockIdx.y;        // head
    const int tid = threadIdx.x, wave = tid >> 6, lane = tid & 63;
    const int lr = lane & 15, lg = lane >> 4;
    const size_t row0 = (size_t)g * 80;

    __shared__ short lds[25920];

    const short* gp[13];
    #pragma unroll
    for (int k = 0; k < 13; ++k) {
        const int s = k * 256 + tid;
        if (s < 640) {
            const int row = s >> 3, p = s & 7;
            gp[k] = Xb + (row0 + row) * 320 + (p ^ (row & 7)) * 8;
        } else if (s < 3200) {
            const int s2 = s - 640;
            const int row = s2 >> 3, p = s2 & 7;
            gp[k] = WqT + (size_t)(n * 320 + row) * 320 + (p ^ (row & 7)) * 8;
        } else {
            gp[k] = Xb;
        }
    }

    const int b = wave;
    bf16x8 bv;
    #pragma unroll
    for (int j = 0; j < 8; ++j) {
        int m = lg * 8 + j; if (m > 19) m = 19;
        bv[j] = xv[(row0 + b * 20 + m) * 256 + n * 16 + lr];
    }

    const int sw = (lr & 7);

    f32x4 acc[5][5] = {};
    for (int ks = 0; ks < 5; ++ks) {
        __syncthreads();
        const int ko = ks * 64;
        #pragma unroll
        for (int k = 0; k < 12; ++k)
            gload16(gp[k] + ko, lds + (size_t)(k * 256 + tid) * 8);
        if (tid < 128)
            gload16(gp[12] + ko, lds + (size_t)(3072 + tid) * 8);
        __syncthreads();
        #pragma unroll
        for (int sub = 0; sub < 2; ++sub) {
            bf16x8 af[5], bfr[5];
            #pragma unroll
            for (int i = 0; i < 5; ++i)
                af[i] = *reinterpret_cast<const bf16x8*>(
                    lds + (i * 16 + lr) * 64 + ((sub * 4 + lg) ^ sw) * 8);
            #pragma unroll
            for (int j = 0; j < 5; ++j)
                bfr[j] = *reinterpret_cast<const bf16x8*>(
                    lds + 5120 + (wave * 80 + j * 16 + lr) * 64 + ((sub * 4 + lg) ^ sw) * 8);
            #pragma unroll
            for (int i = 0; i < 5; ++i)
                #pragma unroll
                for (int j = 0; j < 5; ++j)
                    acc[i][j] = __builtin_amdgcn_mfma_f32_16x16x32_bf16(af[i], bfr[j], acc[i][j], 0, 0, 0);
        }
    }
    __syncthreads();

    #pragma unroll
    for (int i = 0; i < 5; ++i)
        #pragma unroll
        for (int j = 0; j < 5; ++j)
            #pragma unroll
            for (int r = 0; r < 4; ++r)
                lds[(i * 16 + lg * 4 + r) * 324 + wave * 80 + j * 16 + lr] = f2b(acc[i][j][r]);

    const int rA0 = b * 20 + lr;
    int rA1 = b * 20 + 16 + lr; if (rA1 > 79) rA1 = 79;
    bf16x8 xpre0[10], xpre1[10];
    #pragma unroll
    for (int ks = 0; ks < 10; ++ks) {
        xpre0[ks] = *reinterpret_cast<const bf16x8*>(Xb + (row0 + rA0) * 320 + ks * 32 + lg * 8);
        xpre1[ks] = *reinterpret_cast<const bf16x8*>(Xb + (row0 + rA1) * 320 + ks * 32 + lg * 8);
    }
    __syncthreads();

    float w0[2][4], w1[2][4];
    {
        f32x4 s[2][2] = {};
        #pragma unroll
        for (int ks = 0; ks < 10; ++ks) {
            const int kc = ks * 32 + lg * 8;
            bf16x8 a0 = *reinterpret_cast<const bf16x8*>(lds + rA0 * 324 + kc);
            bf16x8 a1 = *reinterpret_cast<const bf16x8*>(lds + rA1 * 324 + kc);
            s[0][0] = __builtin_amdgcn_mfma_f32_16x16x32_bf16(a0, xpre0[ks], s[0][0], 0, 0, 0);
            s[0][1] = __builtin_amdgcn_mfma_f32_16x16x32_bf16(a0, xpre1[ks], s[0][1], 0, 0, 0);
            s[1][0] = __builtin_amdgcn_mfma_f32_16x16x32_bf16(a1, xpre0[ks], s[1][0], 0, 0, 0);
            s[1][1] = __builtin_amdgcn_mfma_f32_16x16x32_bf16(a1, xpre1[ks], s[1][1], 0, 0, 0);
        }

        const float scl = 0.057735026918962584f;  // 1/sqrt(300)
        #pragma unroll
        for (int mts = 0; mts < 2; ++mts) {
            #pragma unroll
            for (int r = 0; r < 4; ++r) {
                float v0 = s[mts][0][r] * scl;
                float v1 = s[mts][1][r] * scl;
                float mx = (lr < 4) ? fmaxf(v0, v1) : v0;
                mx = fmaxf(mx, __shfl_xor(mx, 1));
                mx = fmaxf(mx, __shfl_xor(mx, 2));
                mx = fmaxf(mx, __shfl_xor(mx, 4));
                mx = fmaxf(mx, __shfl_xor(mx, 8));
                float e0 = __expf(v0 - mx);
                float e1 = (lr < 4) ? __expf(v1 - mx) : 0.f;
                float sm = e0 + e1;
                sm += __shfl_xor(sm, 1);
                sm += __shfl_xor(sm, 2);
                sm += __shfl_xor(sm, 4);
                sm += __shfl_xor(sm, 8);
                const float inv = 1.f / sm;
                w0[mts][r] = e0 * inv;
                w1[mts][r] = e1 * inv;
            }
        }
    }

    short* atw = lds + b * 6480;
    {
        int* az = reinterpret_cast<int*>(atw);
        #pragma unroll
        for (int i = 0; i < 9; ++i) {
            const int ix = lane + i * 64;
            if (ix < 544) az[ix] = 0;
        }
    }
    #pragma unroll
    for (int mts = 0; mts < 2; ++mts)
        #pragma unroll
        for (int r = 0; r < 4; ++r) {
            const int row = mts * 16 + lg * 4 + r;
            if (row < LL) {
                atw[row * 34 + lr]      = f2b(w0[mts][r]);
                atw[row * 34 + 16 + lr] = f2b(w1[mts][r]);
            }
        }

    bf16x8 va0 = *reinterpret_cast<const bf16x8*>(atw + lr * 34 + lg * 8);
    bf16x8 va1 = *reinterpret_cast<const bf16x8*>(atw + (16 + lr) * 34 + lg * 8);
    f32x4 z = {0.f, 0.f, 0.f, 0.f};
    f32x4 v0 = __builtin_amdgcn_mfma_f32_16x16x32_bf16(va0, bv, z, 0, 0, 0);
    f32x4 v1 = __builtin_amdgcn_mfma_f32_16x16x32_bf16(va1, bv, z, 0, 0, 0);
    #pragma unroll
    for (int r = 0; r < 4; ++r) {
        const int rowl = lg * 4 + r;
        const size_t o0 = (row0 + b * 20 + rowl) * 256 + n * 16 + lr;
        out1[o0] = v0[r];
        mhb[o0] = f2b(v0[r]);
        const int rowl1 = 16 + lg * 4 + r;
        if (rowl1 < LL) {
            const size_t o1 = (row0 + b * 20 + rowl1) * 256 + n * 16 + lr;
            out1[o1] = v1[r];
            mhb[o1] = f2b(v1[r]);
        }
    }
}

// ---------------------------------------------------------------------------
// gemm_ak2: GEMM mhb*kwb2^T fused with tanh/query partial-dot epilogue.
// Writes s2p[row][colhalf] partial sums; NO ak materialization.
// grid (2,250): blockIdx.x = col-half (0: d 0..127, 1: d 128..255).
// ---------------------------------------------------------------------------
__global__ __launch_bounds__(256, 4) void gemm_ak2(
    const short* __restrict__ mhb,   // [32000][256]
    const short* __restrict__ kwb,   // [256][256]
    const float* __restrict__ keyB,  // [200]
    const float* __restrict__ query, // [200]
    float*       __restrict__ s2p)   // [32000][2] partial sums
{
    const int nt0 = blockIdx.x * 128;
    const int mt0 = blockIdx.y * 128;
    const int tid = threadIdx.x, wave = tid >> 6, lane = tid & 63;
    const int lr = lane & 15, lg = lane >> 4;
    const int wm = wave & 1, wn = wave >> 1;

    __shared__ short sAB[8192];
    __shared__ float part[128][2];

    const int rA = tid >> 2, c = tid & 3;
    const short* aS0 = mhb + (size_t)(mt0 + rA) * 256 + c * 8;
    const short* aS1 = aS0 + (size_t)64 * 256;
    const short* bS0 = kwb + (size_t)(nt0 + rA) * 256 + c * 8;
    const short* bS1 = bS0 + (size_t)64 * 256;
    short* d0 = sAB + tid * 8;
    short* d1 = sAB + (tid + 256) * 8;
    short* d2 = sAB + (tid + 512) * 8;
    short* d3 = sAB + (tid + 768) * 8;

    f32x4 acc[4][4] = {};
    for (int ks = 0; ks < 8; ++ks) {
        __syncthreads();
        const int ko = ks * 32;
        gload16(aS0 + ko, d0);
        gload16(aS1 + ko, d1);
        gload16(bS0 + ko, d2);
        gload16(bS1 + ko, d3);
        __syncthreads();
        bf16x8 af[4], bfr[4];
        #pragma unroll
        for (int i = 0; i < 4; ++i)
            af[i] = *reinterpret_cast<const bf16x8*>(sAB + (wm * 64 + i * 16 + lr) * 32 + lg * 8);
        #pragma unroll
        for (int j = 0; j < 4; ++j)
            bfr[j] = *reinterpret_cast<const bf16x8*>(sAB + 4096 + (wn * 64 + j * 16 + lr) * 32 + lg * 8);
        #pragma unroll
        for (int i = 0; i < 4; ++i)
            #pragma unroll
            for (int j = 0; j < 4; ++j)
                acc[i][j] = __builtin_amdgcn_mfma_f32_16x16x32_bf16(af[i], bfr[j], acc[i][j], 0, 0, 0);
    }

    // epilogue: val[row] = sum_cols query[d]*tanh(acc + keyB[d]);  d < 200 only
    #pragma unroll
    for (int i = 0; i < 4; ++i)
        #pragma unroll
        for (int r = 0; r < 4; ++r) {
            float vsum = 0.f;
            #pragma unroll
            for (int j = 0; j < 4; ++j) {
                const int d = nt0 + wn * 64 + j * 16 + lr;
                if (d < QD)
                    vsum = fmaf(query[d], ftanh(acc[i][j][r] + keyB[d]), vsum);
            }
            // reduce over the 16 lr lanes (lane bits 0..3)
            vsum += __shfl_xor(vsum, 1);
            vsum += __shfl_xor(vsum, 2);
            vsum += __shfl_xor(vsum, 4);
            vsum += __shfl_xor(vsum, 8);
            if (lr == 0)
                part[wm * 64 + i * 16 + lg * 4 + r][wn] = vsum;
        }
    __syncthreads();

    if (tid < 128)
        s2p[(size_t)(mt0 + tid) * 2 + blockIdx.x] = part[tid][0] + part[tid][1];
}

// ---------------------------------------------------------------------------
// pool_final: softmax over s2 + weighted sum from out1.  grid 1600, 256 thr.
// ---------------------------------------------------------------------------
__global__ __launch_bounds__(256) void pool_final(
    const float* __restrict__ s2p,    // [32000][2]
    const float* __restrict__ out1,   // mh fp32
    float*       __restrict__ out2)   // [NBS][256]
{
    const int bs = blockIdx.x;
    const int tid = threadIdx.x;

    __shared__ float s2[LL];

    if (tid < LL) {
        const size_t row = (size_t)bs * 20 + tid;
        s2[tid] = (s2p[row * 2] + s2p[row * 2 + 1]) * 0.07071067811865475f;  // 1/sqrt(200)
    }
    __syncthreads();

    if (tid == 0) {
        float mx = -1e30f;
        #pragma unroll
        for (int l = 0; l < LL; ++l) mx = fmaxf(mx, s2[l]);
        float e[LL], sum = 0.f;
        #pragma unroll
        for (int l = 0; l < LL; ++l) { e[l] = __expf(s2[l] - mx); sum += e[l]; }
        const float inv = 1.f / sum;
        #pragma unroll
        for (int l = 0; l < LL; ++l) s2[l] = e[l] * inv;
    }
    __syncthreads();

    float o = 0.f;
    #pragma unroll
    for (int l = 0; l < LL; ++l)
        o = fmaf(s2[l], out1[((size_t)bs * 20 + l) * 256 + tid], o);
    out2[(size_t)bs * 256 + tid] = o;
}

// ===========================================================================
// FALLBACK (round-3, ~3.4 MB ws)
// ===========================================================================

#define XP 330
#define TP 42
#define AP 34

__global__ __launch_bounds__(1024) void transpose_qw(
    const float* __restrict__ qW, short* __restrict__ wqt)
{
    __shared__ float t[32][33];
    const int n = blockIdx.z;
    const int e0 = blockIdx.x * 32, f0 = blockIdx.y * 32;
    const int tx = threadIdx.x, ty = threadIdx.y;
    const int e = e0 + ty, f = f0 + tx;
    t[ty][tx] = (e < EE && f < EE) ? qW[(size_t)n * EE * EE + e * EE + f] : 0.f;
    __syncthreads();
    const int fo = f0 + ty, eo = e0 + tx;
    if (fo < 304)
        wqt[(size_t)n * 304 * 320 + fo * 320 + eo] = f2b(t[tx][ty]);
}

__global__ void conv_vw(const float* __restrict__ vW, short* __restrict__ wvt) {
    int idx = blockIdx.x * 256 + threadIdx.x;
    if (idx >= NH * VD * 320) return;
    int e = idx % 320;
    int v = (idx / 320) % VD;
    int n = idx / (320 * VD);
    wvt[idx] = (e < EE) ? f2b(vW[(size_t)n * EE * VD + e * VD + v]) : (short)0;
}

__global__ void conv_kw_fb(const float* __restrict__ keyW, short* __restrict__ kwb) {
    int idx = blockIdx.x * 256 + threadIdx.x;
    if (idx >= 256 * 256) return;
    int d = idx >> 8;
    kwb[idx] = (d < QD) ? f2b(keyW[idx]) : (short)0;
}

__global__ __launch_bounds__(512) void nrms_attn_mfma(
    const int*   __restrict__ news,
    const float* __restrict__ emb,
    const short* __restrict__ wqt,
    const float* __restrict__ qB,
    const short* __restrict__ wvt,
    const float* __restrict__ vB,
    float*       __restrict__ out1)
{
    const int bs   = blockIdx.x;
    const int tid  = threadIdx.x;
    const int wave = tid >> 6;
    const int lane = tid & 63;
    const int lr   = lane & 15;
    const int lg   = lane >> 4;

    __shared__ short xs[32][XP];
    __shared__ short xT[320][TP];
    __shared__ short qs[32][XP];
    __shared__ float sc[32][33];
    __shared__ short at[32][AP];

    {
        int* z = (int*)&xs[0][0];
        for (int i = tid; i < 32 * XP / 2; i += 512) z[i] = 0;
        z = (int*)&qs[0][0];
        for (int i = tid; i < 32 * XP / 2; i += 512) z[i] = 0;
        z = (int*)&xT[0][0];
        for (int i = tid; i < 320 * TP / 2; i += 512) z[i] = 0;
    }
    __syncthreads();

    for (int idx = tid; idx < LL * 75; idx += 512) {
        const int l = idx / 75, e4 = (idx % 75) * 4;
        const int row = news[bs * LL + l];
        const float4 v = *reinterpret_cast<const float4*>(emb + (size_t)row * EE + e4);
        const short b0 = f2b(v.x), b1 = f2b(v.y), b2 = f2b(v.z), b3 = f2b(v.w);
        xs[l][e4] = b0; xs[l][e4 + 1] = b1; xs[l][e4 + 2] = b2; xs[l][e4 + 3] = b3;
        xT[e4][l] = b0; xT[e4 + 1][l] = b1; xT[e4 + 2][l] = b2; xT[e4 + 3][l] = b3;
    }
    __syncthreads();

    for (int n = 0; n < NH; ++n) {
        const short* wq = wqt + (size_t)n * 304 * 320;

        for (int p = wave; p < 19; p += 8) {
            f32x4 acc0 = {0.f, 0.f, 0.f, 0.f};
            f32x4 acc1 = {0.f, 0.f, 0.f, 0.f};
            const short* a0p = &xs[lr][lg * 8];
            const short* a1p = &xs[16 + lr][lg * 8];
            const short* bp  = wq + (p * 16 + lr) * 320 + lg * 8;
            #pragma unroll
            for (int k = 0; k < 10; ++k) {
                bf16x8 b  = *reinterpret_cast<const bf16x8*>(bp + k * 32);
                bf16x8 a0 = *reinterpret_cast<const bf16x8*>(a0p + k * 32);
                bf16x8 a1 = *reinterpret_cast<const bf16x8*>(a1p + k * 32);
                acc0 = __builtin_amdgcn_mfma_f32_16x16x32_bf16(a0, b, acc0, 0, 0, 0);
                acc1 = __builtin_amdgcn_mfma_f32_16x16x32_bf16(a1, b, acc1, 0, 0, 0);
            }
            const int col = p * 16 + lr;
            const float bias = (col < EE) ? qB[n * EE + col] : 0.f;
            #pragma unroll
            for (int r = 0; r < 4; ++r) {
                qs[lg * 4 + r][col]      = f2b(acc0[r] + bias);
                qs[16 + lg * 4 + r][col] = f2b(acc1[r] + bias);
            }
        }
        __syncthreads();

        if (wave < 4) {
            const int mt = wave & 1, nt = wave >> 1;
            f32x4 acc = {0.f, 0.f, 0.f, 0.f};
            const short* ap = &qs[mt * 16 + lr][lg * 8];
            const short* bp = &xs[nt * 16 + lr][lg * 8];
            #pragma unroll
            for (int k = 0; k < 10; ++k) {
                bf16x8 a = *reinterpret_cast<const bf16x8*>(ap + k * 32);
                bf16x8 b = *reinterpret_cast<const bf16x8*>(bp + k * 32);
                acc = __builtin_amdgcn_mfma_f32_16x16x32_bf16(a, b, acc, 0, 0, 0);
            }
            #pragma unroll
            for (int r = 0; r < 4; ++r)
                sc[mt * 16 + lg * 4 + r][nt * 16 + lr] = acc[r] * 0.057735026918962584f;
        }
        __syncthreads();

        if (tid < LL) {
            float mx = -1e30f;
            #pragma unroll
            for (int m = 0; m < LL; ++m) mx = fmaxf(mx, sc[tid][m]);
            float ev[LL], sum = 0.f;
            #pragma unroll
            for (int m = 0; m < LL; ++m) { ev[m] = __expf(sc[tid][m] - mx); sum += ev[m]; }
            const float inv = 1.f / sum;
            #pragma unroll
            for (int m = 0; m < LL; ++m) at[tid][m] = f2b(ev[m] * inv);
            #pragma unroll
            for (int m = LL; m < 32; ++m) at[tid][m] = 0;
        } else if (tid < 32) {
            int* zr = (int*)&at[tid][0];
            #pragma unroll
            for (int m = 0; m < 16; ++m) zr[m] = 0;
        }
        __syncthreads();

        for (int p = wave; p < 19; p += 8) {
            bf16x8 b  = *reinterpret_cast<const bf16x8*>(&xT[p * 16 + lr][lg * 8]);
            bf16x8 a0 = *reinterpret_cast<const bf16x8*>(&at[lr][lg * 8]);
            bf16x8 a1 = *reinterpret_cast<const bf16x8*>(&at[16 + lr][lg * 8]);
            f32x4 z = {0.f, 0.f, 0.f, 0.f};
            f32x4 c0 = __builtin_amdgcn_mfma_f32_16x16x32_bf16(a0, b, z, 0, 0, 0);
            f32x4 c1 = __builtin_amdgcn_mfma_f32_16x16x32_bf16(a1, b, z, 0, 0, 0);
            const int col = p * 16 + lr;
            #pragma unroll
            for (int r = 0; r < 4; ++r) {
                qs[lg * 4 + r][col]      = f2b(c0[r]);
                qs[16 + lg * 4 + r][col] = f2b(c1[r]);
            }
        }
        __syncthreads();

        if (wave < 2) {
            const int mt = wave;
            f32x4 acc = {0.f, 0.f, 0.f, 0.f};
            const short* ap = &qs[mt * 16 + lr][lg * 8];
            const short* bp = wvt + (size_t)n * VD * 320 + lr * 320 + lg * 8;
            #pragma unroll
            for (int k = 0; k < 10; ++k) {
                bf16x8 a = *reinterpret_cast<const bf16x8*>(ap + k * 32);
                bf16x8 b = *reinterpret_cast<const bf16x8*>(bp + k * 32);
                acc = __builtin_amdgcn_mfma_f32_16x16x32_bf16(a, b, acc, 0, 0, 0);
            }
            #pragma unroll
            for (int r = 0; r < 4; ++r) {
                const int row = mt * 16 + lg * 4 + r;
                if (row < LL)
                    out1[((size_t)bs * LL + row) * HID + n * VD + lr] = acc[r] + vB[n * VD + lr];
            }
        }
        __syncthreads();
    }
}

__global__ __launch_bounds__(256) void nrms_pool_mfma(
    const float* __restrict__ out1,
    const short* __restrict__ kwb,
    const float* __restrict__ keyB,
    const float* __restrict__ query,
    float*       __restrict__ out2)
{
    const int bs   = blockIdx.x;
    const int tid  = threadIdx.x;
    const int wave = tid >> 6;
    const int lane = tid & 63;
    const int lr   = lane & 15;
    const int lg   = lane >> 4;

    __shared__ float mh[LL][257];
    __shared__ short mhbl[32][264];
    __shared__ float s2p[32];

    for (int i = tid; i < 12 * 128; i += 256) {
        const int r = 20 + i / 128, c = (i % 128) * 2;
        *reinterpret_cast<int*>(&mhbl[r][c]) = 0;
    }
    if (tid < 32) s2p[tid] = 0.f;

    for (int idx = tid; idx < LL * 64; idx += 256) {
        const int l = idx >> 6, h4 = (idx & 63) * 4;
        const float4 v = *reinterpret_cast<const float4*>(out1 + ((size_t)bs * LL + l) * HID + h4);
        mh[l][h4] = v.x; mh[l][h4 + 1] = v.y; mh[l][h4 + 2] = v.z; mh[l][h4 + 3] = v.w;
        mhbl[l][h4] = f2b(v.x); mhbl[l][h4 + 1] = f2b(v.y);
        mhbl[l][h4 + 2] = f2b(v.z); mhbl[l][h4 + 3] = f2b(v.w);
    }
    __syncthreads();

    for (int t = wave; t < 26; t += 4) {
        const int mt = t & 1, nt = t >> 1;
        f32x4 acc = {0.f, 0.f, 0.f, 0.f};
        const short* ap = &mhbl[mt * 16 + lr][lg * 8];
        const short* bp = kwb + (nt * 16 + lr) * 256 + lg * 8;
        #pragma unroll
        for (int k = 0; k < 8; ++k) {
            bf16x8 a = *reinterpret_cast<const bf16x8*>(ap + k * 32);
            bf16x8 b = *reinterpret_cast<const bf16x8*>(bp + k * 32);
            acc = __builtin_amdgcn_mfma_f32_16x16x32_bf16(a, b, acc, 0, 0, 0);
        }
        const int d = nt * 16 + lr;
        const float qd = (d < QD) ? query[d] : 0.f;
        const float kb = (d < QD) ? keyB[d] : 0.f;
        float vals[4];
        #pragma unroll
        for (int r = 0; r < 4; ++r) vals[r] = qd * ftanh(acc[r] + kb);
        #pragma unroll
        for (int off = 1; off < 16; off <<= 1) {
            #pragma unroll
            for (int r = 0; r < 4; ++r) vals[r] += __shfl_xor(vals[r], off);
        }
        if (lr == 0) {
            #pragma unroll
            for (int r = 0; r < 4; ++r)
                atomicAdd(&s2p[mt * 16 + lg * 4 + r], vals[r]);
        }
    }
    __syncthreads();

    if (tid == 0) {
        float mx = -1e30f;
        #pragma unroll
        for (int l = 0; l < LL; ++l) mx = fmaxf(mx, s2p[l] * 0.07071067811865475f);
        float sum = 0.f;
        float e[LL];
        #pragma unroll
        for (int l = 0; l < LL; ++l) { e[l] = __expf(s2p[l] * 0.07071067811865475f - mx); sum += e[l]; }
        const float inv = 1.f / sum;
        #pragma unroll
        for (int l = 0; l < LL; ++l) s2p[l] = e[l] * inv;
    }
    __syncthreads();

    {
        const int h = tid;
        float acc = 0.f;
        #pragma unroll
        for (int l = 0; l < LL; ++l) acc = fmaf(s2p[l], mh[l][h], acc);
        out2[(size_t)bs * HID + h] = acc;
    }
}

// ===========================================================================

extern "C" void kernel_launch(void* const* d_in, const int* in_sizes, int n_in,
                              void* d_out, int out_size, void* d_ws, size_t ws_size,
                              hipStream_t stream) {
    const int*   news  = (const int*)d_in[0];
    const float* emb   = (const float*)d_in[1];
    const float* qW    = (const float*)d_in[2];
    const float* qB    = (const float*)d_in[3];
    const float* vW    = (const float*)d_in[4];
    const float* vB    = (const float*)d_in[5];
    const float* keyW  = (const float*)d_in[6];
    const float* keyB  = (const float*)d_in[7];
    const float* query = (const float*)d_in[8];

    float* out1 = (float*)d_out;            // news_embedding: 8192000 floats
    float* out2 = out1 + 8192000;           // news_repr: 409600 floats

    // base (shorts): Xb 10.24M, WqT 1.6384M, WvT 81920, xv 8.192M,
    //                kwb2 65536, mhb 8.192M, s2p 64000 f32 (=128000 sh)
    const size_t BASE_SH = 10240000ull + 1638400 + 81920 + 8192000
                         + 65536 + 8192000 + 128000;
    const size_t BASE_B  = BASE_SH * 2;    // ~57.1 MB

    if (ws_size >= BASE_B) {
        short* Xb   = (short*)d_ws;
        short* WqT  = Xb + 10240000;
        short* WvT  = WqT + 1638400;
        short* xv   = WvT + 81920;
        short* kwb2 = xv + 8192000;
        short* mhb  = kwb2 + 65536;
        float* s2p  = (float*)(mhb + 8192000);

        hipLaunchKernelGGL(build_all, dim3(10577), dim3(256), 0, stream,
                           news, emb, vW, vB, keyW, Xb, WvT, kwb2);
        hipLaunchKernelGGL(build_wqt_lin, dim3(10, 10, 16), dim3(32, 32), 0, stream, qW, qB, WqT);
        hipLaunchKernelGGL(gemm_xv, dim3(2, 250), dim3(256), 0, stream, Xb, WvT, xv);
        hipLaunchKernelGGL(qsv, dim3(400, 16), dim3(256), 0, stream,
                           Xb, WqT, xv, out1, mhb);
        hipLaunchKernelGGL(gemm_ak2, dim3(2, 250), dim3(256), 0, stream,
                           mhb, kwb2, keyB, query, s2p);
        hipLaunchKernelGGL(pool_final, dim3(NBS), dim3(256), 0, stream, s2p, out1, out2);
    } else {
        short* wqt  = (short*)d_ws;
        short* wvt  = wqt + (size_t)NH * 304 * 320;
        short* kwb2 = wvt + (size_t)NH * VD * 320;

        hipLaunchKernelGGL(transpose_qw, dim3(10, 10, 16), dim3(32, 32), 0, stream, qW, wqt);
        hipLaunchKernelGGL(conv_vw, dim3(320), dim3(256), 0, stream, vW, wvt);
        hipLaunchKernelGGL(conv_kw_fb, dim3(256), dim3(256), 0, stream, keyW, kwb2);
        hipLaunchKernelGGL(nrms_attn_mfma, dim3(NBS), dim3(512), 0, stream,
                           news, emb, wqt, qB, wvt, vB, out1);
        hipLaunchKernelGGL(nrms_pool_mfma, dim3(NBS), dim3(256), 0, stream,
                           out1, kwb2, keyB, query, out2);
    }
}